// Round 17
// baseline (82.351 us; speedup 1.0000x reference)
//
#include <hip/hip_runtime.h>
#include <hip/hip_bf16.h>
#include <cstddef>
#include <cstdint>

constexpr int Bb = 16, Ss = 512, Dd = 256, Hh = 8, HDd = 32, Ff = 682;
constexpr int FKp = 704;            // padded K for down GEMM (682 -> 704 = 11*64)
constexpr float EPSf = 1.1920928955078125e-07f;

typedef short bf8v __attribute__((ext_vector_type(8)));
typedef float f4 __attribute__((ext_vector_type(4)));
using bf16 = __hip_bfloat16;

__device__ inline f4 MFMA(bf8v a, bf8v b, f4 c) {
  return __builtin_amdgcn_mfma_f32_16x16x32_bf16(a, b, c, 0, 0, 0);
}

__device__ __forceinline__ void pack4(bf16* dst, float a, float b, float c, float d) {
  bf16 t[4] = {__float2bfloat16(a), __float2bfloat16(b),
               __float2bfloat16(c), __float2bfloat16(d)};
  *(uint2*)dst = *(const uint2*)t;
}

// ---------------- vectorized weight converts + embed+rmsnorm in ONE launch ----
__global__ __launch_bounds__(256) void k_prep(
    const float* __restrict__ wq, const float* __restrict__ wk,
    const float* __restrict__ wv, const float* __restrict__ wg,
    const float* __restrict__ wu, const float* __restrict__ wd,
    bf16* __restrict__ dqkv, bf16* __restrict__ dgate,
    bf16* __restrict__ dup, bf16* __restrict__ ddown,
    const float* __restrict__ emb, const float* __restrict__ pos,
    const int* __restrict__ tok, const float* __restrict__ w,
    bf16* __restrict__ hb, bf16* __restrict__ xb)
{
  const int b = blockIdx.x, tid = threadIdx.x;
  if (b < 160) {                       // qkv pack
    const int idx4 = (b * 256 + tid) * 4;
    const int row = idx4 >> 8, col = idx4 & 255;
    f4 v = (f4){0.f, 0.f, 0.f, 0.f};
    if (row < 256)      v = *(const f4*)&wq[(size_t)row * 256 + col];
    else if (row < 288) v = *(const f4*)&wk[(size_t)(row - 256) * 256 + col];
    else if (row < 544) v = *(const f4*)&wv[(size_t)(row - 288) * 256 + col];
    pack4(&dqkv[idx4], v[0], v[1], v[2], v[3]);
  } else if (b < 544) {                // gate / up
    const bool isg = b < 352;
    const int idx4 = ((b - (isg ? 160 : 352)) * 256 + tid) * 4;
    const int row = idx4 >> 8, col = idx4 & 255;
    const float* src = isg ? wg : wu;
    f4 v = (f4){0.f, 0.f, 0.f, 0.f};
    if (row < Ff) v = *(const f4*)&src[(size_t)row * 256 + col];
    pack4(&(isg ? dgate : dup)[idx4], v[0], v[1], v[2], v[3]);
  } else if (b < 720) {                // down [256][704], src rows 682 wide
    const int idx4 = ((b - 544) * 256 + tid) * 4;
    const int row = idx4 / FKp, col = idx4 - row * FKp;   // col % 4 == 0
    float v0 = 0.f, v1 = 0.f, v2 = 0.f, v3 = 0.f;
    const float* srow = &wd[(size_t)row * Ff];
    if (col + 0 < Ff) v0 = srow[col + 0];
    if (col + 1 < Ff) v1 = srow[col + 1];
    if (col + 2 < Ff) v2 = srow[col + 2];
    if (col + 3 < Ff) v3 = srow[col + 3];
    pack4(&ddown[idx4], v0, v1, v2, v3);
  } else {                             // embed + rmsnorm, 4 rows/block
    const int row = (b - 720) * 4 + (tid >> 6);
    const int lane = tid & 63;
    const int c = lane * 4;
    const int s = row & (Ss - 1);
    const int t = tok[row];
    const f4 e4 = *(const f4*)&emb[(size_t)t * Dd + c];
    const f4 p4 = *(const f4*)&pos[(size_t)s * Dd + c];
    float v[4];
    float ss = 0.f;
    #pragma unroll
    for (int j = 0; j < 4; j++) { v[j] = e4[j] + p4[j]; ss += v[j] * v[j]; }
    #pragma unroll
    for (int x = 1; x < 64; x <<= 1) ss += __shfl_xor(ss, x);
    const float r = rsqrtf(ss * (1.0f / Dd) + EPSf);
    const f4 w4 = *(const f4*)&w[c];
    const size_t o = (size_t)row * Dd + c;
    pack4(&hb[o], v[0], v[1], v[2], v[3]);
    pack4(&xb[o], v[0] * r * w4[0], v[1] * r * w4[1],
                  v[2] * r * w4[2], v[3] * r * w4[3]);
  }
}

// ---------------- qkv GEMM: BM=128 BN=64 K=256, rope epilogue, V transposed ----
__global__ __launch_bounds__(256) void k_qkv(
    const bf16* __restrict__ A, const bf16* __restrict__ W,
    const float* __restrict__ bias0, const float* __restrict__ bias1,
    const float* __restrict__ bias2,
    const float* __restrict__ cost, const float* __restrict__ sint,
    bf16* __restrict__ ob0, bf16* __restrict__ ob1, bf16* __restrict__ vt)
{
  __shared__ bf16 As[128 * 72];
  __shared__ bf16 Bs[64 * 72];
  const int tid = threadIdx.x, lane = tid & 63, wid = tid >> 6;
  const int l15 = lane & 15, lg = lane >> 4;
  const int m0 = blockIdx.x * 128, n0 = blockIdx.y * 64;
  const int wr = (wid >> 1) * 64, wc = (wid & 1) * 32;
  const int srow = tid >> 3, scol = (tid & 7) * 8;

  f4 acc[4][2];
  #pragma unroll
  for (int i = 0; i < 4; i++)
    #pragma unroll
    for (int j = 0; j < 2; j++) acc[i][j] = (f4){0.f, 0.f, 0.f, 0.f};

  bf8v pa[4], pb[2];
  #pragma unroll
  for (int i = 0; i < 4; i++)
    pa[i] = *(const bf8v*)&A[(size_t)(m0 + srow + i * 32) * 256 + scol];
  #pragma unroll
  for (int i = 0; i < 2; i++)
    pb[i] = *(const bf8v*)&W[(size_t)(n0 + srow + i * 32) * 256 + scol];
  #pragma unroll
  for (int i = 0; i < 4; i++) *(bf8v*)&As[(srow + i * 32) * 72 + scol] = pa[i];
  #pragma unroll
  for (int i = 0; i < 2; i++) *(bf8v*)&Bs[(srow + i * 32) * 72 + scol] = pb[i];
  __syncthreads();

  for (int ks = 0; ks < 4; ks++) {
    if (ks < 3) {
      const int kn = (ks + 1) * 64;
      #pragma unroll
      for (int i = 0; i < 4; i++)
        pa[i] = *(const bf8v*)&A[(size_t)(m0 + srow + i * 32) * 256 + kn + scol];
      #pragma unroll
      for (int i = 0; i < 2; i++)
        pb[i] = *(const bf8v*)&W[(size_t)(n0 + srow + i * 32) * 256 + kn + scol];
    }
    #pragma unroll
    for (int kk = 0; kk < 64; kk += 32) {
      bf8v af[4], bw[2];
      #pragma unroll
      for (int mi = 0; mi < 4; mi++)
        af[mi] = *(const bf8v*)&As[(wr + mi * 16 + l15) * 72 + kk + lg * 8];
      #pragma unroll
      for (int ni = 0; ni < 2; ni++)
        bw[ni] = *(const bf8v*)&Bs[(wc + ni * 16 + l15) * 72 + kk + lg * 8];
      #pragma unroll
      for (int mi = 0; mi < 4; mi++)
        #pragma unroll
        for (int ni = 0; ni < 2; ni++)
          acc[mi][ni] = MFMA(af[mi], bw[ni], acc[mi][ni]);
    }
    __syncthreads();
    if (ks < 3) {
      #pragma unroll
      for (int i = 0; i < 4; i++) *(bf8v*)&As[(srow + i * 32) * 72 + scol] = pa[i];
      #pragma unroll
      for (int i = 0; i < 2; i++) *(bf8v*)&Bs[(srow + i * 32) * 72 + scol] = pb[i];
      __syncthreads();
    }
  }

  #pragma unroll
  for (int mi = 0; mi < 4; mi++) {
    #pragma unroll
    for (int ni = 0; ni < 2; ni++) {
      const int nbase = n0 + wc + ni * 16;
      const int n = nbase + l15;
      if (nbase < 288) {                      // q or k region: rope
        #pragma unroll
        for (int r = 0; r < 4; r++) {
          const int m = m0 + wr + mi * 16 + lg * 4 + r;
          float vb2 = acc[mi][ni][r] + (nbase < 256 ? bias0[n] : bias1[n - 256]);
          int s, hd;
          if (nbase < 256) { const int flat = ((m & 511) << 8) + n; s = (flat >> 5) & 511; hd = n & 31; }
          else             { s = m & 511; hd = n - 256; }
          const float c = cost[s * 32 + hd], sn = sint[s * 32 + hd];
          const float other = __shfl_xor(vb2, 1);
          const float res = (n & 1) ? (other * sn + vb2 * c) : (vb2 * c - other * sn);
          if (nbase < 256) ob0[(size_t)m * 256 + n] = __float2bfloat16(res);
          else             ob1[(size_t)m * 32 + hd] = __float2bfloat16(res);
        }
      } else if (nbase < 544) {               // v region: transpose via C-order reshape
        const int rel = n - 288;              // feature col in vlin, 0..255
        const int hd = rel & 31, rq = rel >> 5;
        const int mb = m0 + wr + mi * 16 + lg * 4;   // base row, mult of 4
        const int b = mb >> 9;
        const float bv = bias2[rel];
        #pragma unroll
        for (int r = 0; r < 4; r++) {
          const int s = (mb + r) & 511;
          // v4[b][h][s4][hd] = vlin[b][s][rel]:  h = s>>6, s4 = (s&63)*8 + rq
          const int hh2 = s >> 6;
          const int s4 = ((s & 63) << 3) + rq;
          vt[((size_t)(b * Hh + hh2) * HDd + hd) * Ss + s4] =
              __float2bfloat16(acc[mi][ni][r] + bv);
        }
      }
    }
  }
}

// ---------------- fused FFN gate+up: BM=128 BN=64 -> g_bf [8192][704] ----
__global__ __launch_bounds__(256) void k_ffn(
    const bf16* __restrict__ A, const bf16* __restrict__ Wg,
    const bf16* __restrict__ Wu,
    const float* __restrict__ bg, const float* __restrict__ bu,
    bf16* __restrict__ out)
{
  __shared__ bf16 As[128 * 72];
  __shared__ bf16 Gs[64 * 72];
  __shared__ bf16 Us[64 * 72];
  const int tid = threadIdx.x, lane = tid & 63, wid = tid >> 6;
  const int l15 = lane & 15, lg = lane >> 4;
  const int m0 = blockIdx.x * 128, n0 = blockIdx.y * 64;
  const int wr = (wid >> 1) * 64, wc = (wid & 1) * 32;
  const int srow = tid >> 3, scol = (tid & 7) * 8;

  f4 accg[4][2], accu[4][2];
  #pragma unroll
  for (int i = 0; i < 4; i++)
    #pragma unroll
    for (int j = 0; j < 2; j++) {
      accg[i][j] = (f4){0.f, 0.f, 0.f, 0.f};
      accu[i][j] = (f4){0.f, 0.f, 0.f, 0.f};
    }

  bf8v pa[4], pg[2], pu[2];
  #pragma unroll
  for (int i = 0; i < 4; i++)
    pa[i] = *(const bf8v*)&A[(size_t)(m0 + srow + i * 32) * 256 + scol];
  #pragma unroll
  for (int i = 0; i < 2; i++) {
    pg[i] = *(const bf8v*)&Wg[(size_t)(n0 + srow + i * 32) * 256 + scol];
    pu[i] = *(const bf8v*)&Wu[(size_t)(n0 + srow + i * 32) * 256 + scol];
  }
  #pragma unroll
  for (int i = 0; i < 4; i++) *(bf8v*)&As[(srow + i * 32) * 72 + scol] = pa[i];
  #pragma unroll
  for (int i = 0; i < 2; i++) {
    *(bf8v*)&Gs[(srow + i * 32) * 72 + scol] = pg[i];
    *(bf8v*)&Us[(srow + i * 32) * 72 + scol] = pu[i];
  }
  __syncthreads();

  for (int ks = 0; ks < 4; ks++) {
    if (ks < 3) {
      const int kn = (ks + 1) * 64;
      #pragma unroll
      for (int i = 0; i < 4; i++)
        pa[i] = *(const bf8v*)&A[(size_t)(m0 + srow + i * 32) * 256 + kn + scol];
      #pragma unroll
      for (int i = 0; i < 2; i++) {
        pg[i] = *(const bf8v*)&Wg[(size_t)(n0 + srow + i * 32) * 256 + kn + scol];
        pu[i] = *(const bf8v*)&Wu[(size_t)(n0 + srow + i * 32) * 256 + kn + scol];
      }
    }
    #pragma unroll
    for (int kk = 0; kk < 64; kk += 32) {
      bf8v af[4], bgf[2], buf[2];
      #pragma unroll
      for (int mi = 0; mi < 4; mi++)
        af[mi] = *(const bf8v*)&As[(wr + mi * 16 + l15) * 72 + kk + lg * 8];
      #pragma unroll
      for (int ni = 0; ni < 2; ni++) {
        bgf[ni] = *(const bf8v*)&Gs[(wc + ni * 16 + l15) * 72 + kk + lg * 8];
        buf[ni] = *(const bf8v*)&Us[(wc + ni * 16 + l15) * 72 + kk + lg * 8];
      }
      #pragma unroll
      for (int mi = 0; mi < 4; mi++)
        #pragma unroll
        for (int ni = 0; ni < 2; ni++) {
          accg[mi][ni] = MFMA(af[mi], bgf[ni], accg[mi][ni]);
          accu[mi][ni] = MFMA(af[mi], buf[ni], accu[mi][ni]);
        }
    }
    __syncthreads();
    if (ks < 3) {
      #pragma unroll
      for (int i = 0; i < 4; i++) *(bf8v*)&As[(srow + i * 32) * 72 + scol] = pa[i];
      #pragma unroll
      for (int i = 0; i < 2; i++) {
        *(bf8v*)&Gs[(srow + i * 32) * 72 + scol] = pg[i];
        *(bf8v*)&Us[(srow + i * 32) * 72 + scol] = pu[i];
      }
      __syncthreads();
    }
  }

  #pragma unroll
  for (int ni = 0; ni < 2; ni++) {
    const int n = n0 + wc + ni * 16 + l15;
    const float bgv = (n < Ff) ? bg[n] : 0.f;
    const float buv = (n < Ff) ? bu[n] : 0.f;
    #pragma unroll
    for (int mi = 0; mi < 4; mi++) {
      #pragma unroll
      for (int r = 0; r < 4; r++) {
        const int m = m0 + wr + mi * 16 + lg * 4 + r;
        float res = 0.f;
        if (n < Ff) {
          const float gv = accg[mi][ni][r] + bgv;
          const float uv = accu[mi][ni][r] + buv;
          res = gv / (1.f + __expf(-gv)) * uv;
        }
        out[(size_t)m * FKp + n] = __float2bfloat16(res);
      }
    }
  }
}

// ---------------- down GEMM: BM=64 BN=64 K=704, +bias +resid(bf16) -> out f32 ----
__global__ __launch_bounds__(256) void k_down(
    const bf16* __restrict__ A, const bf16* __restrict__ W,
    const float* __restrict__ bias, const bf16* __restrict__ resid,
    float* __restrict__ out)
{
  __shared__ bf16 As[64 * 72];
  __shared__ bf16 Bs[64 * 72];
  const int tid = threadIdx.x, lane = tid & 63, wid = tid >> 6;
  const int l15 = lane & 15, lg = lane >> 4;
  const int m0 = blockIdx.x * 64, n0 = blockIdx.y * 64;
  const int wr = (wid >> 1) * 32, wc = (wid & 1) * 32;
  const int srow = tid >> 3, scol = (tid & 7) * 8;

  f4 acc[2][2];
  #pragma unroll
  for (int i = 0; i < 2; i++)
    #pragma unroll
    for (int j = 0; j < 2; j++) acc[i][j] = (f4){0.f, 0.f, 0.f, 0.f};

  bf8v pa[2], pb[2];
  #pragma unroll
  for (int i = 0; i < 2; i++) {
    pa[i] = *(const bf8v*)&A[(size_t)(m0 + srow + i * 32) * FKp + scol];
    pb[i] = *(const bf8v*)&W[(size_t)(n0 + srow + i * 32) * FKp + scol];
  }
  #pragma unroll
  for (int i = 0; i < 2; i++) {
    *(bf8v*)&As[(srow + i * 32) * 72 + scol] = pa[i];
    *(bf8v*)&Bs[(srow + i * 32) * 72 + scol] = pb[i];
  }
  __syncthreads();

  for (int ks = 0; ks < 11; ks++) {
    if (ks < 10) {
      const int kn = (ks + 1) * 64;
      #pragma unroll
      for (int i = 0; i < 2; i++) {
        pa[i] = *(const bf8v*)&A[(size_t)(m0 + srow + i * 32) * FKp + kn + scol];
        pb[i] = *(const bf8v*)&W[(size_t)(n0 + srow + i * 32) * FKp + kn + scol];
      }
    }
    #pragma unroll
    for (int kk = 0; kk < 64; kk += 32) {
      bf8v af[2], bw[2];
      #pragma unroll
      for (int mi = 0; mi < 2; mi++)
        af[mi] = *(const bf8v*)&As[(wr + mi * 16 + l15) * 72 + kk + lg * 8];
      #pragma unroll
      for (int ni = 0; ni < 2; ni++)
        bw[ni] = *(const bf8v*)&Bs[(wc + ni * 16 + l15) * 72 + kk + lg * 8];
      #pragma unroll
      for (int mi = 0; mi < 2; mi++)
        #pragma unroll
        for (int ni = 0; ni < 2; ni++)
          acc[mi][ni] = MFMA(af[mi], bw[ni], acc[mi][ni]);
    }
    __syncthreads();
    if (ks < 10) {
      #pragma unroll
      for (int i = 0; i < 2; i++) {
        *(bf8v*)&As[(srow + i * 32) * 72 + scol] = pa[i];
        *(bf8v*)&Bs[(srow + i * 32) * 72 + scol] = pb[i];
      }
      __syncthreads();
    }
  }

  #pragma unroll
  for (int ni = 0; ni < 2; ni++) {
    const int n = n0 + wc + ni * 16 + l15;
    const float bv = bias[n];
    #pragma unroll
    for (int mi = 0; mi < 2; mi++) {
      #pragma unroll
      for (int r = 0; r < 4; r++) {
        const int m = m0 + wr + mi * 16 + lg * 4 + r;
        out[(size_t)m * 256 + n] = acc[mi][ni][r] + bv +
            __bfloat162float(resid[(size_t)m * 256 + n]);
      }
    }
  }
}

// ---------------- fused attention + add + rmsnorm, KVBLK=128, defer-max ------
// grid (32, B), 512 threads = 8 waves; wave = head wid, q-rows [(31-bx)*16,+16).
__global__ __launch_bounds__(512) void k_attn_norm(
    const bf16* __restrict__ q, const bf16* __restrict__ k,
    const bf16* __restrict__ vt, const bf16* __restrict__ hb,
    const float* __restrict__ w, bf16* __restrict__ x2b)
{
  __shared__ bf16 Ps[8][16 * 136];     // per wave P tile [q16][128+8 pad] = 34.8 KB
  const int tid = threadIdx.x, lane = tid & 63, wid = tid >> 6;  // wid = head
  const int l15 = lane & 15, lg = lane >> 4;
  const int bb = blockIdx.y;
  const int bh = bb * Hh + wid;
  const int qrow = (31 - blockIdx.x) * 16;   // longest blocks dispatch first
  const int lt = qrow >> 7;                  // 128-key tiles
  const float scale = 0.17677669529663687f;

  const bf16* kg = k + (size_t)bb * Ss * HDd;
  const bf16* vg = vt + (size_t)bh * (Ss * HDd);

  const bf8v qf = *(const bf8v*)&q[((size_t)bh * Ss + qrow + l15) * HDd + lg * 8];

  f4 oacc[2];
  oacc[0] = (f4){0.f, 0.f, 0.f, 0.f};
  oacc[1] = (f4){0.f, 0.f, 0.f, 0.f};
  float m = -3.0e38f, l = 0.f;

  for (int ti = 0; ti <= lt; ti++) {
    const int t0 = ti * 128;

    f4 sf[8];
    __builtin_amdgcn_s_setprio(1);
    #pragma unroll
    for (int tf = 0; tf < 8; tf++) {
      const bf8v kf = *(const bf8v*)&kg[(size_t)(t0 + tf * 16 + l15) * HDd + lg * 8];
      sf[tf] = MFMA(kf, qf, (f4){0.f, 0.f, 0.f, 0.f});
    }
    __builtin_amdgcn_s_setprio(0);

    // prefetch V fragments (latency hides under softmax)
    bf8v vb[4][2];
    #pragma unroll
    for (int kt = 0; kt < 4; kt++)
      #pragma unroll
      for (int hf = 0; hf < 2; hf++)
        vb[kt][hf] = *(const bf8v*)&vg[(size_t)(hf * 16 + l15) * Ss + t0 + kt * 32 + lg * 8];

    float pm = -3.0e38f;
    if (ti == lt) {
      #pragma unroll
      for (int tf = 0; tf < 8; tf++)
        #pragma unroll
        for (int r = 0; r < 4; r++) {
          float sv = sf[tf][r] * scale;
          if (t0 + tf * 16 + lg * 4 + r > qrow + l15) sv = -3.0e38f;
          sf[tf][r] = sv;
          pm = fmaxf(pm, sv);
        }
    } else {
      #pragma unroll
      for (int tf = 0; tf < 8; tf++)
        #pragma unroll
        for (int r = 0; r < 4; r++) {
          const float sv = sf[tf][r] * scale;
          sf[tf][r] = sv;
          pm = fmaxf(pm, sv);
        }
    }
    pm = fmaxf(pm, __shfl_xor(pm, 16));
    pm = fmaxf(pm, __shfl_xor(pm, 32));

    // defer-max (T13): only rescale when the max actually grew past THR=8
    if (!__all(pm - m <= 8.0f)) {
      const float nm = fmaxf(m, pm);
      const float corr = __expf(m - nm);
      m = nm;
      l *= corr;
      float corrT[4];
      #pragma unroll
      for (int r = 0; r < 4; r++) corrT[r] = __shfl(corr, lg * 4 + r);
      #pragma unroll
      for (int hf = 0; hf < 2; hf++)
        #pragma unroll
        for (int r = 0; r < 4; r++) oacc[hf][r] *= corrT[r];
    }

    float ls = 0.f;
    #pragma unroll
    for (int tf = 0; tf < 8; tf++)
      #pragma unroll
      for (int r = 0; r < 4; r++) {
        const float p = __expf(sf[tf][r] - m);
        sf[tf][r] = p;
        ls += p;
      }
    ls += __shfl_xor(ls, 16);
    ls += __shfl_xor(ls, 32);
    l += ls;

    #pragma unroll
    for (int tf = 0; tf < 8; tf++) {
      bf16 t4[4];
      #pragma unroll
      for (int r = 0; r < 4; r++) t4[r] = __float2bfloat16(sf[tf][r]);
      *(uint2*)&Ps[wid][l15 * 136 + tf * 16 + lg * 4] = *(const uint2*)t4;
    }

    __builtin_amdgcn_s_setprio(1);
    #pragma unroll
    for (int kt = 0; kt < 4; kt++) {
      const bf8v pv = *(const bf8v*)&Ps[wid][l15 * 136 + kt * 32 + lg * 8];
      #pragma unroll
      for (int hf = 0; hf < 2; hf++)
        oacc[hf] = MFMA(pv, vb[kt][hf], oacc[hf]);
    }
    __builtin_amdgcn_s_setprio(0);
  }

  // ---- fused add + rmsnorm in the reshaped (B,S,D) space ----
  float lT[4];
  #pragma unroll
  for (int r = 0; r < 4; r++) lT[r] = __shfl(l, lg * 4 + r);

  const size_t bbase = (size_t)bb * (Ss * Dd);
  float vv[2][4];
  #pragma unroll
  for (int hf = 0; hf < 2; hf++)
    #pragma unroll
    for (int r = 0; r < 4; r++) {
      const int frow = qrow + lg * 4 + r;
      const int hd = hf * 16 + l15;
      vv[hf][r] = oacc[hf][r] / lT[r] +
          __bfloat162float(hb[bbase + (size_t)wid * 16384 + frow * 32 + hd]);
    }

  float ss = 0.f;
  #pragma unroll
  for (int hf = 0; hf < 2; hf++)
    #pragma unroll
    for (int r = 0; r < 4; r++) ss += vv[hf][r] * vv[hf][r];
  #pragma unroll
  for (int x = 1; x < 32; x <<= 1) ss += __shfl_xor(ss, x);   // half-wave sum
  const float rr = rsqrtf(ss * (1.0f / Dd) + EPSf);

  #pragma unroll
  for (int hf = 0; hf < 2; hf++)
    #pragma unroll
    for (int r = 0; r < 4; r++) {
      const int frow = qrow + lg * 4 + r;
      const int hd = hf * 16 + l15;
      const int d2 = ((frow & 7) << 5) + hd;
      x2b[bbase + (size_t)wid * 16384 + frow * 32 + hd] =
          __float2bfloat16(vv[hf][r] * rr * w[d2]);
    }
}

extern "C" void kernel_launch(void* const* d_in, const int* in_sizes, int n_in,
                              void* d_out, int out_size, void* d_ws, size_t ws_size,
                              hipStream_t stream)
{
  const float* emb     = (const float*)d_in[0];
  const float* pos_emb = (const float*)d_in[1];
  const float* attn_w  = (const float*)d_in[2];
  const float* wq      = (const float*)d_in[3];
  const float* bq      = (const float*)d_in[4];
  const float* wk      = (const float*)d_in[5];
  const float* bk      = (const float*)d_in[6];
  const float* wv      = (const float*)d_in[7];
  const float* bv      = (const float*)d_in[8];
  const float* cos_t   = (const float*)d_in[9];
  const float* sin_t   = (const float*)d_in[10];
  const float* ffn_w   = (const float*)d_in[11];
  const float* w_gate  = (const float*)d_in[12];
  const float* b_gate  = (const float*)d_in[13];
  const float* w_up    = (const float*)d_in[14];
  const float* b_up    = (const float*)d_in[15];
  const float* w_down  = (const float*)d_in[16];
  const float* b_down  = (const float*)d_in[17];
  const int*   tok     = (const int*)d_in[18];
  float* out = (float*)d_out;

  const size_t NT = (size_t)Bb * Ss;   // 8192
  char* base = (char*)d_ws;
  size_t off = 0;
  auto alloc = [&](size_t bytes) {
    void* r = base + off;
    off = (off + bytes + 255) & ~(size_t)255;
    return r;
  };
  bf16*  h_bf   = (bf16*)alloc(NT * Dd * 2);
  bf16*  x_bf   = (bf16*)alloc(NT * Dd * 2);
  bf16*  q_bf   = (bf16*)alloc(NT * Dd * 2);
  bf16*  k_bf   = (bf16*)alloc(NT * HDd * 2);
  bf16*  vt_bf  = (bf16*)alloc(NT * Dd * 2);
  bf16*  x2_bf  = (bf16*)alloc(NT * Dd * 2);
  bf16*  g_bf   = (bf16*)alloc(NT * (size_t)FKp * 2);
  bf16*  wqkv_b = (bf16*)alloc((size_t)640 * 256 * 2);
  bf16*  wgate_b= (bf16*)alloc((size_t)768 * 256 * 2);
  bf16*  wup_b  = (bf16*)alloc((size_t)768 * 256 * 2);
  bf16*  wdown_b= (bf16*)alloc((size_t)256 * FKp * 2);

  k_prep<<<dim3(720 + 2048), 256, 0, stream>>>(
      wq, wk, wv, w_gate, w_up, w_down, wqkv_b, wgate_b, wup_b, wdown_b,
      emb, pos_emb, tok, attn_w, h_bf, x_bf);

  k_qkv<<<dim3(NT / 128, 9), 256, 0, stream>>>(
      x_bf, wqkv_b, bq, bk, bv, cos_t, sin_t, q_bf, k_bf, vt_bf);

  k_attn_norm<<<dim3(32, Bb), 512, 0, stream>>>(
      q_bf, k_bf, vt_bf, h_bf, ffn_w, x2_bf);

  k_ffn<<<dim3(NT / 128, 11), 256, 0, stream>>>(
      x2_bf, wgate_b, wup_b, b_gate, b_up, g_bf);

  k_down<<<dim3(NT / 64, 4), 256, 0, stream>>>(
      g_bf, wdown_b, b_down, x2_bf, out);
}

// Round 18
// 80.657 us; speedup vs baseline: 1.0210x; 1.0210x over previous
//
#include <hip/hip_runtime.h>
#include <hip/hip_bf16.h>
#include <cstddef>
#include <cstdint>

constexpr int Bb = 16, Ss = 512, Dd = 256, Hh = 8, HDd = 32, Ff = 682;
constexpr int FKp = 704;            // padded K for down GEMM (682 -> 704 = 11*64)
constexpr float EPSf = 1.1920928955078125e-07f;

typedef short bf8v __attribute__((ext_vector_type(8)));
typedef float f4 __attribute__((ext_vector_type(4)));
using bf16 = __hip_bfloat16;

__device__ inline f4 MFMA(bf8v a, bf8v b, f4 c) {
  return __builtin_amdgcn_mfma_f32_16x16x32_bf16(a, b, c, 0, 0, 0);
}

__device__ __forceinline__ void pack4(bf16* dst, float a, float b, float c, float d) {
  bf16 t[4] = {__float2bfloat16(a), __float2bfloat16(b),
               __float2bfloat16(c), __float2bfloat16(d)};
  *(uint2*)dst = *(const uint2*)t;
}

// ---------------- vectorized weight converts + embed+rmsnorm in ONE launch ----
__global__ __launch_bounds__(256) void k_prep(
    const float* __restrict__ wq, const float* __restrict__ wk,
    const float* __restrict__ wv, const float* __restrict__ wg,
    const float* __restrict__ wu, const float* __restrict__ wd,
    bf16* __restrict__ dqkv, bf16* __restrict__ dgate,
    bf16* __restrict__ dup, bf16* __restrict__ ddown,
    const float* __restrict__ emb, const float* __restrict__ pos,
    const int* __restrict__ tok, const float* __restrict__ w,
    bf16* __restrict__ hb, bf16* __restrict__ xb)
{
  const int b = blockIdx.x, tid = threadIdx.x;
  if (b < 160) {                       // qkv pack
    const int idx4 = (b * 256 + tid) * 4;
    const int row = idx4 >> 8, col = idx4 & 255;
    f4 v = (f4){0.f, 0.f, 0.f, 0.f};
    if (row < 256)      v = *(const f4*)&wq[(size_t)row * 256 + col];
    else if (row < 288) v = *(const f4*)&wk[(size_t)(row - 256) * 256 + col];
    else if (row < 544) v = *(const f4*)&wv[(size_t)(row - 288) * 256 + col];
    pack4(&dqkv[idx4], v[0], v[1], v[2], v[3]);
  } else if (b < 544) {                // gate / up
    const bool isg = b < 352;
    const int idx4 = ((b - (isg ? 160 : 352)) * 256 + tid) * 4;
    const int row = idx4 >> 8, col = idx4 & 255;
    const float* src = isg ? wg : wu;
    f4 v = (f4){0.f, 0.f, 0.f, 0.f};
    if (row < Ff) v = *(const f4*)&src[(size_t)row * 256 + col];
    pack4(&(isg ? dgate : dup)[idx4], v[0], v[1], v[2], v[3]);
  } else if (b < 720) {                // down [256][704], src rows 682 wide
    const int idx4 = ((b - 544) * 256 + tid) * 4;
    const int row = idx4 / FKp, col = idx4 - row * FKp;   // col % 4 == 0
    float v0 = 0.f, v1 = 0.f, v2 = 0.f, v3 = 0.f;
    const float* srow = &wd[(size_t)row * Ff];
    if (col + 0 < Ff) v0 = srow[col + 0];
    if (col + 1 < Ff) v1 = srow[col + 1];
    if (col + 2 < Ff) v2 = srow[col + 2];
    if (col + 3 < Ff) v3 = srow[col + 3];
    pack4(&ddown[idx4], v0, v1, v2, v3);
  } else {                             // embed + rmsnorm, 4 rows/block
    const int row = (b - 720) * 4 + (tid >> 6);
    const int lane = tid & 63;
    const int c = lane * 4;
    const int s = row & (Ss - 1);
    const int t = tok[row];
    const f4 e4 = *(const f4*)&emb[(size_t)t * Dd + c];
    const f4 p4 = *(const f4*)&pos[(size_t)s * Dd + c];
    float v[4];
    float ss = 0.f;
    #pragma unroll
    for (int j = 0; j < 4; j++) { v[j] = e4[j] + p4[j]; ss += v[j] * v[j]; }
    #pragma unroll
    for (int x = 1; x < 64; x <<= 1) ss += __shfl_xor(ss, x);
    const float r = rsqrtf(ss * (1.0f / Dd) + EPSf);
    const f4 w4 = *(const f4*)&w[c];
    const size_t o = (size_t)row * Dd + c;
    pack4(&hb[o], v[0], v[1], v[2], v[3]);
    pack4(&xb[o], v[0] * r * w4[0], v[1] * r * w4[1],
                  v[2] * r * w4[2], v[3] * r * w4[3]);
  }
}

// ---------------- qkv GEMM: BM=128 BN=64 K=256, rope epilogue, V transposed ----
__global__ __launch_bounds__(256) void k_qkv(
    const bf16* __restrict__ A, const bf16* __restrict__ W,
    const float* __restrict__ bias0, const float* __restrict__ bias1,
    const float* __restrict__ bias2,
    const float* __restrict__ cost, const float* __restrict__ sint,
    bf16* __restrict__ ob0, bf16* __restrict__ ob1, bf16* __restrict__ vt)
{
  __shared__ bf16 As[128 * 72];
  __shared__ bf16 Bs[64 * 72];
  const int tid = threadIdx.x, lane = tid & 63, wid = tid >> 6;
  const int l15 = lane & 15, lg = lane >> 4;
  const int m0 = blockIdx.x * 128, n0 = blockIdx.y * 64;
  const int wr = (wid >> 1) * 64, wc = (wid & 1) * 32;
  const int srow = tid >> 3, scol = (tid & 7) * 8;

  f4 acc[4][2];
  #pragma unroll
  for (int i = 0; i < 4; i++)
    #pragma unroll
    for (int j = 0; j < 2; j++) acc[i][j] = (f4){0.f, 0.f, 0.f, 0.f};

  bf8v pa[4], pb[2];
  #pragma unroll
  for (int i = 0; i < 4; i++)
    pa[i] = *(const bf8v*)&A[(size_t)(m0 + srow + i * 32) * 256 + scol];
  #pragma unroll
  for (int i = 0; i < 2; i++)
    pb[i] = *(const bf8v*)&W[(size_t)(n0 + srow + i * 32) * 256 + scol];
  #pragma unroll
  for (int i = 0; i < 4; i++) *(bf8v*)&As[(srow + i * 32) * 72 + scol] = pa[i];
  #pragma unroll
  for (int i = 0; i < 2; i++) *(bf8v*)&Bs[(srow + i * 32) * 72 + scol] = pb[i];
  __syncthreads();

  for (int ks = 0; ks < 4; ks++) {
    if (ks < 3) {
      const int kn = (ks + 1) * 64;
      #pragma unroll
      for (int i = 0; i < 4; i++)
        pa[i] = *(const bf8v*)&A[(size_t)(m0 + srow + i * 32) * 256 + kn + scol];
      #pragma unroll
      for (int i = 0; i < 2; i++)
        pb[i] = *(const bf8v*)&W[(size_t)(n0 + srow + i * 32) * 256 + kn + scol];
    }
    #pragma unroll
    for (int kk = 0; kk < 64; kk += 32) {
      bf8v af[4], bw[2];
      #pragma unroll
      for (int mi = 0; mi < 4; mi++)
        af[mi] = *(const bf8v*)&As[(wr + mi * 16 + l15) * 72 + kk + lg * 8];
      #pragma unroll
      for (int ni = 0; ni < 2; ni++)
        bw[ni] = *(const bf8v*)&Bs[(wc + ni * 16 + l15) * 72 + kk + lg * 8];
      #pragma unroll
      for (int mi = 0; mi < 4; mi++)
        #pragma unroll
        for (int ni = 0; ni < 2; ni++)
          acc[mi][ni] = MFMA(af[mi], bw[ni], acc[mi][ni]);
    }
    __syncthreads();
    if (ks < 3) {
      #pragma unroll
      for (int i = 0; i < 4; i++) *(bf8v*)&As[(srow + i * 32) * 72 + scol] = pa[i];
      #pragma unroll
      for (int i = 0; i < 2; i++) *(bf8v*)&Bs[(srow + i * 32) * 72 + scol] = pb[i];
      __syncthreads();
    }
  }

  #pragma unroll
  for (int mi = 0; mi < 4; mi++) {
    #pragma unroll
    for (int ni = 0; ni < 2; ni++) {
      const int nbase = n0 + wc + ni * 16;
      const int n = nbase + l15;
      if (nbase < 288) {                      // q or k region: rope
        #pragma unroll
        for (int r = 0; r < 4; r++) {
          const int m = m0 + wr + mi * 16 + lg * 4 + r;
          float vb2 = acc[mi][ni][r] + (nbase < 256 ? bias0[n] : bias1[n - 256]);
          int s, hd;
          if (nbase < 256) { const int flat = ((m & 511) << 8) + n; s = (flat >> 5) & 511; hd = n & 31; }
          else             { s = m & 511; hd = n - 256; }
          const float c = cost[s * 32 + hd], sn = sint[s * 32 + hd];
          const float other = __shfl_xor(vb2, 1);
          const float res = (n & 1) ? (other * sn + vb2 * c) : (vb2 * c - other * sn);
          if (nbase < 256) ob0[(size_t)m * 256 + n] = __float2bfloat16(res);
          else             ob1[(size_t)m * 32 + hd] = __float2bfloat16(res);
        }
      } else if (nbase < 544) {               // v region: transpose via C-order reshape
        const int rel = n - 288;              // feature col in vlin, 0..255
        const int hd = rel & 31, rq = rel >> 5;
        const int mb = m0 + wr + mi * 16 + lg * 4;   // base row, mult of 4
        const int b = mb >> 9;
        const float bv = bias2[rel];
        #pragma unroll
        for (int r = 0; r < 4; r++) {
          const int s = (mb + r) & 511;
          // v4[b][h][s4][hd] = vlin[b][s][rel]:  h = s>>6, s4 = (s&63)*8 + rq
          const int hh2 = s >> 6;
          const int s4 = ((s & 63) << 3) + rq;
          vt[((size_t)(b * Hh + hh2) * HDd + hd) * Ss + s4] =
              __float2bfloat16(acc[mi][ni][r] + bv);
        }
      }
    }
  }
}

// ---------------- fused FFN gate+up: BM=128 BN=32 -> g_bf [8192][704] ----
__global__ __launch_bounds__(256) void k_ffn(
    const bf16* __restrict__ A, const bf16* __restrict__ Wg,
    const bf16* __restrict__ Wu,
    const float* __restrict__ bg, const float* __restrict__ bu,
    bf16* __restrict__ out)
{
  __shared__ bf16 As[128 * 72];
  __shared__ bf16 Gs[32 * 72];
  __shared__ bf16 Us[32 * 72];
  const int tid = threadIdx.x, lane = tid & 63, wid = tid >> 6;
  const int l15 = lane & 15, lg = lane >> 4;
  const int m0 = blockIdx.x * 128, n0 = blockIdx.y * 32;
  const int wr = wid * 32;             // 4 waves x 32 rows
  const int srow = tid >> 3, scol = (tid & 7) * 8;
  const int wrow = tid >> 3;           // 0..31 for W staging (256 thr = 32x8)

  f4 accg[2][2], accu[2][2];
  #pragma unroll
  for (int i = 0; i < 2; i++)
    #pragma unroll
    for (int j = 0; j < 2; j++) {
      accg[i][j] = (f4){0.f, 0.f, 0.f, 0.f};
      accu[i][j] = (f4){0.f, 0.f, 0.f, 0.f};
    }

  bf8v pa[4], pg, pu;
  #pragma unroll
  for (int i = 0; i < 4; i++)
    pa[i] = *(const bf8v*)&A[(size_t)(m0 + srow + i * 32) * 256 + scol];
  pg = *(const bf8v*)&Wg[(size_t)(n0 + wrow) * 256 + scol];
  pu = *(const bf8v*)&Wu[(size_t)(n0 + wrow) * 256 + scol];
  #pragma unroll
  for (int i = 0; i < 4; i++) *(bf8v*)&As[(srow + i * 32) * 72 + scol] = pa[i];
  *(bf8v*)&Gs[wrow * 72 + scol] = pg;
  *(bf8v*)&Us[wrow * 72 + scol] = pu;
  __syncthreads();

  for (int ks = 0; ks < 4; ks++) {
    if (ks < 3) {
      const int kn = (ks + 1) * 64;
      #pragma unroll
      for (int i = 0; i < 4; i++)
        pa[i] = *(const bf8v*)&A[(size_t)(m0 + srow + i * 32) * 256 + kn + scol];
      pg = *(const bf8v*)&Wg[(size_t)(n0 + wrow) * 256 + kn + scol];
      pu = *(const bf8v*)&Wu[(size_t)(n0 + wrow) * 256 + kn + scol];
    }
    #pragma unroll
    for (int kk = 0; kk < 64; kk += 32) {
      bf8v af[2], bgf[2], buf[2];
      #pragma unroll
      for (int mi = 0; mi < 2; mi++)
        af[mi] = *(const bf8v*)&As[(wr + mi * 16 + l15) * 72 + kk + lg * 8];
      #pragma unroll
      for (int ni = 0; ni < 2; ni++) {
        bgf[ni] = *(const bf8v*)&Gs[(ni * 16 + l15) * 72 + kk + lg * 8];
        buf[ni] = *(const bf8v*)&Us[(ni * 16 + l15) * 72 + kk + lg * 8];
      }
      #pragma unroll
      for (int mi = 0; mi < 2; mi++)
        #pragma unroll
        for (int ni = 0; ni < 2; ni++) {
          accg[mi][ni] = MFMA(af[mi], bgf[ni], accg[mi][ni]);
          accu[mi][ni] = MFMA(af[mi], buf[ni], accu[mi][ni]);
        }
    }
    __syncthreads();
    if (ks < 3) {
      #pragma unroll
      for (int i = 0; i < 4; i++) *(bf8v*)&As[(srow + i * 32) * 72 + scol] = pa[i];
      *(bf8v*)&Gs[wrow * 72 + scol] = pg;
      *(bf8v*)&Us[wrow * 72 + scol] = pu;
      __syncthreads();
    }
  }

  #pragma unroll
  for (int ni = 0; ni < 2; ni++) {
    const int n = n0 + ni * 16 + l15;
    const float bgv = (n < Ff) ? bg[n] : 0.f;
    const float buv = (n < Ff) ? bu[n] : 0.f;
    #pragma unroll
    for (int mi = 0; mi < 2; mi++) {
      #pragma unroll
      for (int r = 0; r < 4; r++) {
        const int m = m0 + wr + mi * 16 + lg * 4 + r;
        float res = 0.f;
        if (n < Ff) {
          const float gv = accg[mi][ni][r] + bgv;
          const float uv = accu[mi][ni][r] + buv;
          res = gv / (1.f + __expf(-gv)) * uv;
        }
        out[(size_t)m * FKp + n] = __float2bfloat16(res);
      }
    }
  }
}

// ---------------- down GEMM: BM=64 BN=32 K=704, +bias +resid(bf16) -> out f32 ----
__global__ __launch_bounds__(256) void k_down(
    const bf16* __restrict__ A, const bf16* __restrict__ W,
    const float* __restrict__ bias, const bf16* __restrict__ resid,
    float* __restrict__ out)
{
  __shared__ bf16 As[64 * 72];
  __shared__ bf16 Bs[32 * 72];
  const int tid = threadIdx.x, lane = tid & 63, wid = tid >> 6;
  const int l15 = lane & 15, lg = lane >> 4;
  const int m0 = blockIdx.x * 64, n0 = blockIdx.y * 32;
  const int wr = (wid >> 1) * 32, wc = (wid & 1) * 16;
  const int srow = tid >> 3, scol = (tid & 7) * 8;   // srow 0..31
  const int wrow = tid >> 3;

  f4 acc[2];
  acc[0] = (f4){0.f, 0.f, 0.f, 0.f};
  acc[1] = (f4){0.f, 0.f, 0.f, 0.f};

  bf8v pa[2], pb;
  #pragma unroll
  for (int i = 0; i < 2; i++)
    pa[i] = *(const bf8v*)&A[(size_t)(m0 + srow + i * 32) * FKp + scol];
  pb = *(const bf8v*)&W[(size_t)(n0 + wrow) * FKp + scol];
  #pragma unroll
  for (int i = 0; i < 2; i++)
    *(bf8v*)&As[(srow + i * 32) * 72 + scol] = pa[i];
  *(bf8v*)&Bs[wrow * 72 + scol] = pb;
  __syncthreads();

  for (int ks = 0; ks < 11; ks++) {
    if (ks < 10) {
      const int kn = (ks + 1) * 64;
      #pragma unroll
      for (int i = 0; i < 2; i++)
        pa[i] = *(const bf8v*)&A[(size_t)(m0 + srow + i * 32) * FKp + kn + scol];
      pb = *(const bf8v*)&W[(size_t)(n0 + wrow) * FKp + kn + scol];
    }
    #pragma unroll
    for (int kk = 0; kk < 64; kk += 32) {
      bf8v af[2], bw;
      #pragma unroll
      for (int mi = 0; mi < 2; mi++)
        af[mi] = *(const bf8v*)&As[(wr + mi * 16 + l15) * 72 + kk + lg * 8];
      bw = *(const bf8v*)&Bs[(wc + l15) * 72 + kk + lg * 8];
      #pragma unroll
      for (int mi = 0; mi < 2; mi++)
        acc[mi] = MFMA(af[mi], bw, acc[mi]);
    }
    __syncthreads();
    if (ks < 10) {
      #pragma unroll
      for (int i = 0; i < 2; i++)
        *(bf8v*)&As[(srow + i * 32) * 72 + scol] = pa[i];
      *(bf8v*)&Bs[wrow * 72 + scol] = pb;
      __syncthreads();
    }
  }

  const int n = n0 + wc + l15;
  const float bv = bias[n];
  #pragma unroll
  for (int mi = 0; mi < 2; mi++) {
    #pragma unroll
    for (int r = 0; r < 4; r++) {
      const int m = m0 + wr + mi * 16 + lg * 4 + r;
      out[(size_t)m * 256 + n] = acc[mi][r] + bv +
          __bfloat162float(resid[(size_t)m * 256 + n]);
    }
  }
}

// ---------------- fused attention + add + rmsnorm -> x2_bf only ----------------
// grid (32, B), 512 threads = 8 waves; wave = head wid, q-rows [(31-bx)*16,+16).
// o.reshape(B,S,D) is C-order: flat = h*16384 + s*32 + hd; a wave's 16 rows x
// 32 hd = exactly TWO full (B,S,D) rows (half-wave each) -> butterfly rmsnorm.
__global__ __launch_bounds__(512) void k_attn_norm(
    const bf16* __restrict__ q, const bf16* __restrict__ k,
    const bf16* __restrict__ vt, const bf16* __restrict__ hb,
    const float* __restrict__ w, bf16* __restrict__ x2b)
{
  __shared__ bf16 Ps[8][16 * 72];      // per wave P tile (18.4 KB)
  const int tid = threadIdx.x, lane = tid & 63, wid = tid >> 6;  // wid = head
  const int l15 = lane & 15, lg = lane >> 4;
  const int bb = blockIdx.y;
  const int bh = bb * Hh + wid;
  const int qrow = (31 - blockIdx.x) * 16;   // longest blocks dispatch first
  const int lt = (qrow + 15) >> 6;
  const float scale = 0.17677669529663687f;

  const bf16* kg = k + (size_t)bb * Ss * HDd;
  const bf16* vg = vt + (size_t)bh * (Ss * HDd);

  const bf8v qf = *(const bf8v*)&q[((size_t)bh * Ss + qrow + l15) * HDd + lg * 8];

  f4 oacc[2];
  oacc[0] = (f4){0.f, 0.f, 0.f, 0.f};
  oacc[1] = (f4){0.f, 0.f, 0.f, 0.f};
  float m = -3.0e38f, l = 0.f;

  for (int ti = 0; ti <= lt; ti++) {
    const int t0 = ti * 64;

    f4 sf[4];
    __builtin_amdgcn_s_setprio(1);
    #pragma unroll
    for (int tf = 0; tf < 4; tf++) {
      const bf8v kf = *(const bf8v*)&kg[(size_t)(t0 + tf * 16 + l15) * HDd + lg * 8];
      sf[tf] = MFMA(kf, qf, (f4){0.f, 0.f, 0.f, 0.f});
    }
    __builtin_amdgcn_s_setprio(0);

    bf8v vb[2][2];
    #pragma unroll
    for (int kt = 0; kt < 2; kt++)
      #pragma unroll
      for (int hf = 0; hf < 2; hf++)
        vb[kt][hf] = *(const bf8v*)&vg[(size_t)(hf * 16 + l15) * Ss + t0 + kt * 32 + lg * 8];

    float pm = -3.0e38f;
    if (ti == lt) {
      #pragma unroll
      for (int tf = 0; tf < 4; tf++)
        #pragma unroll
        for (int r = 0; r < 4; r++) {
          float sv = sf[tf][r] * scale;
          if (t0 + tf * 16 + lg * 4 + r > qrow + l15) sv = -3.0e38f;
          sf[tf][r] = sv;
          pm = fmaxf(pm, sv);
        }
    } else {
      #pragma unroll
      for (int tf = 0; tf < 4; tf++)
        #pragma unroll
        for (int r = 0; r < 4; r++) {
          const float sv = sf[tf][r] * scale;
          sf[tf][r] = sv;
          pm = fmaxf(pm, sv);
        }
    }
    pm = fmaxf(pm, __shfl_xor(pm, 16));
    pm = fmaxf(pm, __shfl_xor(pm, 32));

    const float nm = fmaxf(m, pm);
    const float corr = __expf(m - nm);
    m = nm;

    float ls = 0.f;
    #pragma unroll
    for (int tf = 0; tf < 4; tf++)
      #pragma unroll
      for (int r = 0; r < 4; r++) {
        const float p = __expf(sf[tf][r] - m);
        sf[tf][r] = p;
        ls += p;
      }
    ls += __shfl_xor(ls, 16);
    ls += __shfl_xor(ls, 32);
    l = l * corr + ls;

    #pragma unroll
    for (int tf = 0; tf < 4; tf++) {
      bf16 t4[4];
      #pragma unroll
      for (int r = 0; r < 4; r++) t4[r] = __float2bfloat16(sf[tf][r]);
      *(uint2*)&Ps[wid][l15 * 72 + tf * 16 + lg * 4] = *(const uint2*)t4;
    }

    float corrT[4];
    #pragma unroll
    for (int r = 0; r < 4; r++) corrT[r] = __shfl(corr, lg * 4 + r);
    #pragma unroll
    for (int hf = 0; hf < 2; hf++)
      #pragma unroll
      for (int r = 0; r < 4; r++) oacc[hf][r] *= corrT[r];

    __builtin_amdgcn_s_setprio(1);
    #pragma unroll
    for (int kt = 0; kt < 2; kt++) {
      const bf8v pv = *(const bf8v*)&Ps[wid][l15 * 72 + kt * 32 + lg * 8];
      #pragma unroll
      for (int hf = 0; hf < 2; hf++)
        oacc[hf] = MFMA(pv, vb[kt][hf], oacc[hf]);
    }
    __builtin_amdgcn_s_setprio(0);
  }

  // ---- fused add + rmsnorm in the reshaped (B,S,D) space ----
  float lT[4];
  #pragma unroll
  for (int r = 0; r < 4; r++) lT[r] = __shfl(l, lg * 4 + r);

  const size_t bbase = (size_t)bb * (Ss * Dd);
  float vv[2][4];
  #pragma unroll
  for (int hf = 0; hf < 2; hf++)
    #pragma unroll
    for (int r = 0; r < 4; r++) {
      const int frow = qrow + lg * 4 + r;
      const int hd = hf * 16 + l15;
      vv[hf][r] = oacc[hf][r] / lT[r] +
          __bfloat162float(hb[bbase + (size_t)wid * 16384 + frow * 32 + hd]);
    }

  float ss = 0.f;
  #pragma unroll
  for (int hf = 0; hf < 2; hf++)
    #pragma unroll
    for (int r = 0; r < 4; r++) ss += vv[hf][r] * vv[hf][r];
  #pragma unroll
  for (int x = 1; x < 32; x <<= 1) ss += __shfl_xor(ss, x);   // half-wave sum
  const float rr = rsqrtf(ss * (1.0f / Dd) + EPSf);

  #pragma unroll
  for (int hf = 0; hf < 2; hf++)
    #pragma unroll
    for (int r = 0; r < 4; r++) {
      const int frow = qrow + lg * 4 + r;
      const int hd = hf * 16 + l15;
      const int d2 = ((frow & 7) << 5) + hd;
      x2b[bbase + (size_t)wid * 16384 + frow * 32 + hd] =
          __float2bfloat16(vv[hf][r] * rr * w[d2]);
    }
}

extern "C" void kernel_launch(void* const* d_in, const int* in_sizes, int n_in,
                              void* d_out, int out_size, void* d_ws, size_t ws_size,
                              hipStream_t stream)
{
  const float* emb     = (const float*)d_in[0];
  const float* pos_emb = (const float*)d_in[1];
  const float* attn_w  = (const float*)d_in[2];
  const float* wq      = (const float*)d_in[3];
  const float* bq      = (const float*)d_in[4];
  const float* wk      = (const float*)d_in[5];
  const float* bk      = (const float*)d_in[6];
  const float* wv      = (const float*)d_in[7];
  const float* bv      = (const float*)d_in[8];
  const float* cos_t   = (const float*)d_in[9];
  const float* sin_t   = (const float*)d_in[10];
  const float* ffn_w   = (const float*)d_in[11];
  const float* w_gate  = (const float*)d_in[12];
  const float* b_gate  = (const float*)d_in[13];
  const float* w_up    = (const float*)d_in[14];
  const float* b_up    = (const float*)d_in[15];
  const float* w_down  = (const float*)d_in[16];
  const float* b_down  = (const float*)d_in[17];
  const int*   tok     = (const int*)d_in[18];
  float* out = (float*)d_out;

  const size_t NT = (size_t)Bb * Ss;   // 8192
  char* base = (char*)d_ws;
  size_t off = 0;
  auto alloc = [&](size_t bytes) {
    void* r = base + off;
    off = (off + bytes + 255) & ~(size_t)255;
    return r;
  };
  bf16*  h_bf   = (bf16*)alloc(NT * Dd * 2);
  bf16*  x_bf   = (bf16*)alloc(NT * Dd * 2);
  bf16*  q_bf   = (bf16*)alloc(NT * Dd * 2);
  bf16*  k_bf   = (bf16*)alloc(NT * HDd * 2);
  bf16*  vt_bf  = (bf16*)alloc(NT * Dd * 2);
  bf16*  x2_bf  = (bf16*)alloc(NT * Dd * 2);
  bf16*  g_bf   = (bf16*)alloc(NT * (size_t)FKp * 2);
  bf16*  wqkv_b = (bf16*)alloc((size_t)640 * 256 * 2);
  bf16*  wgate_b= (bf16*)alloc((size_t)768 * 256 * 2);
  bf16*  wup_b  = (bf16*)alloc((size_t)768 * 256 * 2);
  bf16*  wdown_b= (bf16*)alloc((size_t)256 * FKp * 2);

  k_prep<<<dim3(720 + 2048), 256, 0, stream>>>(
      wq, wk, wv, w_gate, w_up, w_down, wqkv_b, wgate_b, wup_b, wdown_b,
      emb, pos_emb, tok, attn_w, h_bf, x_bf);

  k_qkv<<<dim3(NT / 128, 9), 256, 0, stream>>>(
      x_bf, wqkv_b, bq, bk, bv, cos_t, sin_t, q_bf, k_bf, vt_bf);

  k_attn_norm<<<dim3(32, Bb), 512, 0, stream>>>(
      q_bf, k_bf, vt_bf, h_bf, ffn_w, x2_bf);

  k_ffn<<<dim3(NT / 128, 22), 256, 0, stream>>>(
      x2_bf, wgate_b, wup_b, b_gate, b_up, g_bf);

  k_down<<<dim3(NT / 64, 8), 256, 0, stream>>>(
      g_bf, wdown_b, b_down, x2_bf, out);
}

// Round 20
// 76.875 us; speedup vs baseline: 1.0712x; 1.0492x over previous
//
#include <hip/hip_runtime.h>
#include <hip/hip_bf16.h>
#include <cstddef>
#include <cstdint>

constexpr int Bb = 16, Ss = 512, Dd = 256, Hh = 8, HDd = 32, Ff = 682;
constexpr int FKp = 704;            // padded K for down GEMM (682 -> 704 = 11*64)
constexpr float EPSf = 1.1920928955078125e-07f;

typedef short bf8v __attribute__((ext_vector_type(8)));
typedef float f4 __attribute__((ext_vector_type(4)));
using bf16 = __hip_bfloat16;

__device__ inline f4 MFMA(bf8v a, bf8v b, f4 c) {
  return __builtin_amdgcn_mfma_f32_16x16x32_bf16(a, b, c, 0, 0, 0);
}

__device__ __forceinline__ void pack4(bf16* dst, float a, float b, float c, float d) {
  bf16 t[4] = {__float2bfloat16(a), __float2bfloat16(b),
               __float2bfloat16(c), __float2bfloat16(d)};
  *(uint2*)dst = *(const uint2*)t;
}

// ---------------- vectorized weight converts + embed+rmsnorm in ONE launch ----
__global__ __launch_bounds__(256) void k_prep(
    const float* __restrict__ wq, const float* __restrict__ wk,
    const float* __restrict__ wv, const float* __restrict__ wg,
    const float* __restrict__ wu, const float* __restrict__ wd,
    bf16* __restrict__ dqkv, bf16* __restrict__ dgate,
    bf16* __restrict__ dup, bf16* __restrict__ ddown,
    const float* __restrict__ emb, const float* __restrict__ pos,
    const int* __restrict__ tok, const float* __restrict__ w,
    bf16* __restrict__ hb, bf16* __restrict__ xb)
{
  const int b = blockIdx.x, tid = threadIdx.x;
  if (b < 160) {                       // qkv pack
    const int idx4 = (b * 256 + tid) * 4;
    const int row = idx4 >> 8, col = idx4 & 255;
    f4 v = (f4){0.f, 0.f, 0.f, 0.f};
    if (row < 256)      v = *(const f4*)&wq[(size_t)row * 256 + col];
    else if (row < 288) v = *(const f4*)&wk[(size_t)(row - 256) * 256 + col];
    else if (row < 544) v = *(const f4*)&wv[(size_t)(row - 288) * 256 + col];
    pack4(&dqkv[idx4], v[0], v[1], v[2], v[3]);
  } else if (b < 544) {                // gate / up
    const bool isg = b < 352;
    const int idx4 = ((b - (isg ? 160 : 352)) * 256 + tid) * 4;
    const int row = idx4 >> 8, col = idx4 & 255;
    const float* src = isg ? wg : wu;
    f4 v = (f4){0.f, 0.f, 0.f, 0.f};
    if (row < Ff) v = *(const f4*)&src[(size_t)row * 256 + col];
    pack4(&(isg ? dgate : dup)[idx4], v[0], v[1], v[2], v[3]);
  } else if (b < 720) {                // down [256][704], src rows 682 wide
    const int idx4 = ((b - 544) * 256 + tid) * 4;
    const int row = idx4 / FKp, col = idx4 - row * FKp;   // col % 4 == 0
    float v0 = 0.f, v1 = 0.f, v2 = 0.f, v3 = 0.f;
    const float* srow = &wd[(size_t)row * Ff];
    if (col + 0 < Ff) v0 = srow[col + 0];
    if (col + 1 < Ff) v1 = srow[col + 1];
    if (col + 2 < Ff) v2 = srow[col + 2];
    if (col + 3 < Ff) v3 = srow[col + 3];
    pack4(&ddown[idx4], v0, v1, v2, v3);
  } else {                             // embed + rmsnorm, 4 rows/block
    const int row = (b - 720) * 4 + (tid >> 6);
    const int lane = tid & 63;
    const int c = lane * 4;
    const int s = row & (Ss - 1);
    const int t = tok[row];
    const f4 e4 = *(const f4*)&emb[(size_t)t * Dd + c];
    const f4 p4 = *(const f4*)&pos[(size_t)s * Dd + c];
    float v[4];
    float ss = 0.f;
    #pragma unroll
    for (int j = 0; j < 4; j++) { v[j] = e4[j] + p4[j]; ss += v[j] * v[j]; }
    #pragma unroll
    for (int x = 1; x < 64; x <<= 1) ss += __shfl_xor(ss, x);
    const float r = rsqrtf(ss * (1.0f / Dd) + EPSf);
    const f4 w4 = *(const f4*)&w[c];
    const size_t o = (size_t)row * Dd + c;
    pack4(&hb[o], v[0], v[1], v[2], v[3]);
    pack4(&xb[o], v[0] * r * w4[0], v[1] * r * w4[1],
                  v[2] * r * w4[2], v[3] * r * w4[3]);
  }
}

// ---------------- qkv GEMM: BM=64 BN=64 K=256, rope epilogue, V transposed ----
__global__ __launch_bounds__(256) void k_qkv(
    const bf16* __restrict__ A, const bf16* __restrict__ W,
    const float* __restrict__ bias0, const float* __restrict__ bias1,
    const float* __restrict__ bias2,
    const float* __restrict__ cost, const float* __restrict__ sint,
    bf16* __restrict__ ob0, bf16* __restrict__ ob1, bf16* __restrict__ vt)
{
  __shared__ bf16 As[64 * 72];
  __shared__ bf16 Bs[64 * 72];
  const int tid = threadIdx.x, lane = tid & 63, wid = tid >> 6;
  const int l15 = lane & 15, lg = lane >> 4;
  const int m0 = blockIdx.x * 64, n0 = blockIdx.y * 64;
  const int wr = (wid >> 1) * 32, wc = (wid & 1) * 32;
  const int srow = tid >> 3, scol = (tid & 7) * 8;   // srow 0..31

  f4 acc[2][2];
  #pragma unroll
  for (int i = 0; i < 2; i++)
    #pragma unroll
    for (int j = 0; j < 2; j++) acc[i][j] = (f4){0.f, 0.f, 0.f, 0.f};

  bf8v pa[2], pb[2];
  #pragma unroll
  for (int i = 0; i < 2; i++) {
    pa[i] = *(const bf8v*)&A[(size_t)(m0 + srow + i * 32) * 256 + scol];
    pb[i] = *(const bf8v*)&W[(size_t)(n0 + srow + i * 32) * 256 + scol];
  }
  #pragma unroll
  for (int i = 0; i < 2; i++) {
    *(bf8v*)&As[(srow + i * 32) * 72 + scol] = pa[i];
    *(bf8v*)&Bs[(srow + i * 32) * 72 + scol] = pb[i];
  }
  __syncthreads();

  for (int ks = 0; ks < 4; ks++) {
    if (ks < 3) {
      const int kn = (ks + 1) * 64;
      #pragma unroll
      for (int i = 0; i < 2; i++) {
        pa[i] = *(const bf8v*)&A[(size_t)(m0 + srow + i * 32) * 256 + kn + scol];
        pb[i] = *(const bf8v*)&W[(size_t)(n0 + srow + i * 32) * 256 + kn + scol];
      }
    }
    #pragma unroll
    for (int kk = 0; kk < 64; kk += 32) {
      bf8v af[2], bw[2];
      #pragma unroll
      for (int mi = 0; mi < 2; mi++)
        af[mi] = *(const bf8v*)&As[(wr + mi * 16 + l15) * 72 + kk + lg * 8];
      #pragma unroll
      for (int ni = 0; ni < 2; ni++)
        bw[ni] = *(const bf8v*)&Bs[(wc + ni * 16 + l15) * 72 + kk + lg * 8];
      #pragma unroll
      for (int mi = 0; mi < 2; mi++)
        #pragma unroll
        for (int ni = 0; ni < 2; ni++)
          acc[mi][ni] = MFMA(af[mi], bw[ni], acc[mi][ni]);
    }
    __syncthreads();
    if (ks < 3) {
      #pragma unroll
      for (int i = 0; i < 2; i++) {
        *(bf8v*)&As[(srow + i * 32) * 72 + scol] = pa[i];
        *(bf8v*)&Bs[(srow + i * 32) * 72 + scol] = pb[i];
      }
      __syncthreads();
    }
  }

  #pragma unroll
  for (int mi = 0; mi < 2; mi++) {
    #pragma unroll
    for (int ni = 0; ni < 2; ni++) {
      const int nbase = n0 + wc + ni * 16;
      const int n = nbase + l15;
      if (nbase < 288) {                      // q or k region: rope
        #pragma unroll
        for (int r = 0; r < 4; r++) {
          const int m = m0 + wr + mi * 16 + lg * 4 + r;
          float vb2 = acc[mi][ni][r] + (nbase < 256 ? bias0[n] : bias1[n - 256]);
          int s, hd;
          if (nbase < 256) { const int flat = ((m & 511) << 8) + n; s = (flat >> 5) & 511; hd = n & 31; }
          else             { s = m & 511; hd = n - 256; }
          const float c = cost[s * 32 + hd], sn = sint[s * 32 + hd];
          const float other = __shfl_xor(vb2, 1);
          const float res = (n & 1) ? (other * sn + vb2 * c) : (vb2 * c - other * sn);
          if (nbase < 256) ob0[(size_t)m * 256 + n] = __float2bfloat16(res);
          else             ob1[(size_t)m * 32 + hd] = __float2bfloat16(res);
        }
      } else if (nbase < 544) {               // v region: transpose via C-order reshape
        const int rel = n - 288;              // feature col in vlin, 0..255
        const int hd = rel & 31, rq = rel >> 5;
        const int mb = m0 + wr + mi * 16 + lg * 4;   // base row, mult of 4
        const int b = mb >> 9;
        const float bv = bias2[rel];
        #pragma unroll
        for (int r = 0; r < 4; r++) {
          const int s = (mb + r) & 511;
          // v4[b][h][s4][hd] = vlin[b][s][rel]:  h = s>>6, s4 = (s&63)*8 + rq
          const int hh2 = s >> 6;
          const int s4 = ((s & 63) << 3) + rq;
          vt[((size_t)(b * Hh + hh2) * HDd + hd) * Ss + s4] =
              __float2bfloat16(acc[mi][ni][r] + bv);
        }
      }
    }
  }
}

// ---------------- fused FFN gate+up: BM=128 BN=32 -> g_bf [8192][704] ----
__global__ __launch_bounds__(256) void k_ffn(
    const bf16* __restrict__ A, const bf16* __restrict__ Wg,
    const bf16* __restrict__ Wu,
    const float* __restrict__ bg, const float* __restrict__ bu,
    bf16* __restrict__ out)
{
  __shared__ bf16 As[128 * 72];
  __shared__ bf16 Gs[32 * 72];
  __shared__ bf16 Us[32 * 72];
  const int tid = threadIdx.x, lane = tid & 63, wid = tid >> 6;
  const int l15 = lane & 15, lg = lane >> 4;
  const int m0 = blockIdx.x * 128, n0 = blockIdx.y * 32;
  const int wr = wid * 32;             // 4 waves x 32 rows
  const int srow = tid >> 3, scol = (tid & 7) * 8;
  const int wrow = tid >> 3;           // 0..31 for W staging (256 thr = 32x8)

  f4 accg[2][2], accu[2][2];
  #pragma unroll
  for (int i = 0; i < 2; i++)
    #pragma unroll
    for (int j = 0; j < 2; j++) {
      accg[i][j] = (f4){0.f, 0.f, 0.f, 0.f};
      accu[i][j] = (f4){0.f, 0.f, 0.f, 0.f};
    }

  bf8v pa[4], pg, pu;
  #pragma unroll
  for (int i = 0; i < 4; i++)
    pa[i] = *(const bf8v*)&A[(size_t)(m0 + srow + i * 32) * 256 + scol];
  pg = *(const bf8v*)&Wg[(size_t)(n0 + wrow) * 256 + scol];
  pu = *(const bf8v*)&Wu[(size_t)(n0 + wrow) * 256 + scol];
  #pragma unroll
  for (int i = 0; i < 4; i++) *(bf8v*)&As[(srow + i * 32) * 72 + scol] = pa[i];
  *(bf8v*)&Gs[wrow * 72 + scol] = pg;
  *(bf8v*)&Us[wrow * 72 + scol] = pu;
  __syncthreads();

  for (int ks = 0; ks < 4; ks++) {
    if (ks < 3) {
      const int kn = (ks + 1) * 64;
      #pragma unroll
      for (int i = 0; i < 4; i++)
        pa[i] = *(const bf8v*)&A[(size_t)(m0 + srow + i * 32) * 256 + kn + scol];
      pg = *(const bf8v*)&Wg[(size_t)(n0 + wrow) * 256 + kn + scol];
      pu = *(const bf8v*)&Wu[(size_t)(n0 + wrow) * 256 + kn + scol];
    }
    #pragma unroll
    for (int kk = 0; kk < 64; kk += 32) {
      bf8v af[2], bgf[2], buf[2];
      #pragma unroll
      for (int mi = 0; mi < 2; mi++)
        af[mi] = *(const bf8v*)&As[(wr + mi * 16 + l15) * 72 + kk + lg * 8];
      #pragma unroll
      for (int ni = 0; ni < 2; ni++) {
        bgf[ni] = *(const bf8v*)&Gs[(ni * 16 + l15) * 72 + kk + lg * 8];
        buf[ni] = *(const bf8v*)&Us[(ni * 16 + l15) * 72 + kk + lg * 8];
      }
      #pragma unroll
      for (int mi = 0; mi < 2; mi++)
        #pragma unroll
        for (int ni = 0; ni < 2; ni++) {
          accg[mi][ni] = MFMA(af[mi], bgf[ni], accg[mi][ni]);
          accu[mi][ni] = MFMA(af[mi], buf[ni], accu[mi][ni]);
        }
    }
    __syncthreads();
    if (ks < 3) {
      #pragma unroll
      for (int i = 0; i < 4; i++) *(bf8v*)&As[(srow + i * 32) * 72 + scol] = pa[i];
      *(bf8v*)&Gs[wrow * 72 + scol] = pg;
      *(bf8v*)&Us[wrow * 72 + scol] = pu;
      __syncthreads();
    }
  }

  #pragma unroll
  for (int ni = 0; ni < 2; ni++) {
    const int n = n0 + ni * 16 + l15;
    const float bgv = (n < Ff) ? bg[n] : 0.f;
    const float buv = (n < Ff) ? bu[n] : 0.f;
    #pragma unroll
    for (int mi = 0; mi < 2; mi++) {
      #pragma unroll
      for (int r = 0; r < 4; r++) {
        const int m = m0 + wr + mi * 16 + lg * 4 + r;
        float res = 0.f;
        if (n < Ff) {
          const float gv = accg[mi][ni][r] + bgv;
          const float uv = accu[mi][ni][r] + buv;
          res = gv / (1.f + __expf(-gv)) * uv;
        }
        out[(size_t)m * FKp + n] = __float2bfloat16(res);
      }
    }
  }
}

// ---------------- down GEMM: BM=64 BN=32 K=704, +bias +resid(bf16) -> out f32 ----
__global__ __launch_bounds__(256) void k_down(
    const bf16* __restrict__ A, const bf16* __restrict__ W,
    const float* __restrict__ bias, const bf16* __restrict__ resid,
    float* __restrict__ out)
{
  __shared__ bf16 As[64 * 72];
  __shared__ bf16 Bs[32 * 72];
  const int tid = threadIdx.x, lane = tid & 63, wid = tid >> 6;
  const int l15 = lane & 15, lg = lane >> 4;
  const int m0 = blockIdx.x * 64, n0 = blockIdx.y * 32;
  const int wr = (wid >> 1) * 32, wc = (wid & 1) * 16;
  const int srow = tid >> 3, scol = (tid & 7) * 8;   // srow 0..31
  const int wrow = tid >> 3;

  f4 acc[2];
  acc[0] = (f4){0.f, 0.f, 0.f, 0.f};
  acc[1] = (f4){0.f, 0.f, 0.f, 0.f};

  bf8v pa[2], pb;
  #pragma unroll
  for (int i = 0; i < 2; i++)
    pa[i] = *(const bf8v*)&A[(size_t)(m0 + srow + i * 32) * FKp + scol];
  pb = *(const bf8v*)&W[(size_t)(n0 + wrow) * FKp + scol];
  #pragma unroll
  for (int i = 0; i < 2; i++)
    *(bf8v*)&As[(srow + i * 32) * 72 + scol] = pa[i];
  *(bf8v*)&Bs[wrow * 72 + scol] = pb;
  __syncthreads();

  for (int ks = 0; ks < 11; ks++) {
    if (ks < 10) {
      const int kn = (ks + 1) * 64;
      #pragma unroll
      for (int i = 0; i < 2; i++)
        pa[i] = *(const bf8v*)&A[(size_t)(m0 + srow + i * 32) * FKp + kn + scol];
      pb = *(const bf8v*)&W[(size_t)(n0 + wrow) * FKp + kn + scol];
    }
    #pragma unroll
    for (int kk = 0; kk < 64; kk += 32) {
      bf8v af[2], bw;
      #pragma unroll
      for (int mi = 0; mi < 2; mi++)
        af[mi] = *(const bf8v*)&As[(wr + mi * 16 + l15) * 72 + kk + lg * 8];
      bw = *(const bf8v*)&Bs[(wc + l15) * 72 + kk + lg * 8];
      #pragma unroll
      for (int mi = 0; mi < 2; mi++)
        acc[mi] = MFMA(af[mi], bw, acc[mi]);
    }
    __syncthreads();
    if (ks < 10) {
      #pragma unroll
      for (int i = 0; i < 2; i++)
        *(bf8v*)&As[(srow + i * 32) * 72 + scol] = pa[i];
      *(bf8v*)&Bs[wrow * 72 + scol] = pb;
      __syncthreads();
    }
  }

  const int n = n0 + wc + l15;
  const float bv = bias[n];
  #pragma unroll
  for (int mi = 0; mi < 2; mi++) {
    #pragma unroll
    for (int r = 0; r < 4; r++) {
      const int m = m0 + wr + mi * 16 + lg * 4 + r;
      out[(size_t)m * 256 + n] = acc[mi][r] + bv +
          __bfloat162float(resid[(size_t)m * 256 + n]);
    }
  }
}

// ---------------- fused attention + add + rmsnorm -> x2_bf only ----------------
// grid (32, B), 512 threads = 8 waves; wave = head wid, q-rows [(31-bx)*16,+16).
// o.reshape(B,S,D) is C-order: flat = h*16384 + s*32 + hd; a wave's 16 rows x
// 32 hd = exactly TWO full (B,S,D) rows (half-wave each) -> butterfly rmsnorm.
__global__ __launch_bounds__(512) void k_attn_norm(
    const bf16* __restrict__ q, const bf16* __restrict__ k,
    const bf16* __restrict__ vt, const bf16* __restrict__ hb,
    const float* __restrict__ w, bf16* __restrict__ x2b)
{
  __shared__ bf16 Ps[8][16 * 72];      // per wave P tile (18.4 KB)
  const int tid = threadIdx.x, lane = tid & 63, wid = tid >> 6;  // wid = head
  const int l15 = lane & 15, lg = lane >> 4;
  const int bb = blockIdx.y;
  const int bh = bb * Hh + wid;
  const int qrow = (31 - blockIdx.x) * 16;   // longest blocks dispatch first
  const int lt = (qrow + 15) >> 6;
  const float scale = 0.17677669529663687f;

  const bf16* kg = k + (size_t)bb * Ss * HDd;
  const bf16* vg = vt + (size_t)bh * (Ss * HDd);

  const bf8v qf = *(const bf8v*)&q[((size_t)bh * Ss + qrow + l15) * HDd + lg * 8];

  f4 oacc[2];
  oacc[0] = (f4){0.f, 0.f, 0.f, 0.f};
  oacc[1] = (f4){0.f, 0.f, 0.f, 0.f};
  float m = -3.0e38f, l = 0.f;

  for (int ti = 0; ti <= lt; ti++) {
    const int t0 = ti * 64;

    f4 sf[4];
    __builtin_amdgcn_s_setprio(1);
    #pragma unroll
    for (int tf = 0; tf < 4; tf++) {
      const bf8v kf = *(const bf8v*)&kg[(size_t)(t0 + tf * 16 + l15) * HDd + lg * 8];
      sf[tf] = MFMA(kf, qf, (f4){0.f, 0.f, 0.f, 0.f});
    }
    __builtin_amdgcn_s_setprio(0);

    bf8v vb[2][2];
    #pragma unroll
    for (int kt = 0; kt < 2; kt++)
      #pragma unroll
      for (int hf = 0; hf < 2; hf++)
        vb[kt][hf] = *(const bf8v*)&vg[(size_t)(hf * 16 + l15) * Ss + t0 + kt * 32 + lg * 8];

    float pm = -3.0e38f;
    if (ti == lt) {
      #pragma unroll
      for (int tf = 0; tf < 4; tf++)
        #pragma unroll
        for (int r = 0; r < 4; r++) {
          float sv = sf[tf][r] * scale;
          if (t0 + tf * 16 + lg * 4 + r > qrow + l15) sv = -3.0e38f;
          sf[tf][r] = sv;
          pm = fmaxf(pm, sv);
        }
    } else {
      #pragma unroll
      for (int tf = 0; tf < 4; tf++)
        #pragma unroll
        for (int r = 0; r < 4; r++) {
          const float sv = sf[tf][r] * scale;
          sf[tf][r] = sv;
          pm = fmaxf(pm, sv);
        }
    }
    pm = fmaxf(pm, __shfl_xor(pm, 16));
    pm = fmaxf(pm, __shfl_xor(pm, 32));

    const float nm = fmaxf(m, pm);
    const float corr = __expf(m - nm);
    m = nm;

    float ls = 0.f;
    #pragma unroll
    for (int tf = 0; tf < 4; tf++)
      #pragma unroll
      for (int r = 0; r < 4; r++) {
        const float p = __expf(sf[tf][r] - m);
        sf[tf][r] = p;
        ls += p;
      }
    ls += __shfl_xor(ls, 16);
    ls += __shfl_xor(ls, 32);
    l = l * corr + ls;

    #pragma unroll
    for (int tf = 0; tf < 4; tf++) {
      bf16 t4[4];
      #pragma unroll
      for (int r = 0; r < 4; r++) t4[r] = __float2bfloat16(sf[tf][r]);
      *(uint2*)&Ps[wid][l15 * 72 + tf * 16 + lg * 4] = *(const uint2*)t4;
    }

    float corrT[4];
    #pragma unroll
    for (int r = 0; r < 4; r++) corrT[r] = __shfl(corr, lg * 4 + r);
    #pragma unroll
    for (int hf = 0; hf < 2; hf++)
      #pragma unroll
      for (int r = 0; r < 4; r++) oacc[hf][r] *= corrT[r];

    __builtin_amdgcn_s_setprio(1);
    #pragma unroll
    for (int kt = 0; kt < 2; kt++) {
      const bf8v pv = *(const bf8v*)&Ps[wid][l15 * 72 + kt * 32 + lg * 8];
      #pragma unroll
      for (int hf = 0; hf < 2; hf++)
        oacc[hf] = MFMA(pv, vb[kt][hf], oacc[hf]);
    }
    __builtin_amdgcn_s_setprio(0);
  }

  // ---- fused add + rmsnorm in the reshaped (B,S,D) space ----
  float lT[4];
  #pragma unroll
  for (int r = 0; r < 4; r++) lT[r] = __shfl(l, lg * 4 + r);

  const size_t bbase = (size_t)bb * (Ss * Dd);
  float vv[2][4];
  #pragma unroll
  for (int hf = 0; hf < 2; hf++)
    #pragma unroll
    for (int r = 0; r < 4; r++) {
      const int frow = qrow + lg * 4 + r;
      const int hd = hf * 16 + l15;
      vv[hf][r] = oacc[hf][r] / lT[r] +
          __bfloat162float(hb[bbase + (size_t)wid * 16384 + frow * 32 + hd]);
    }

  float ss = 0.f;
  #pragma unroll
  for (int hf = 0; hf < 2; hf++)
    #pragma unroll
    for (int r = 0; r < 4; r++) ss += vv[hf][r] * vv[hf][r];
  #pragma unroll
  for (int x = 1; x < 32; x <<= 1) ss += __shfl_xor(ss, x);   // half-wave sum
  const float rr = rsqrtf(ss * (1.0f / Dd) + EPSf);

  #pragma unroll
  for (int hf = 0; hf < 2; hf++)
    #pragma unroll
    for (int r = 0; r < 4; r++) {
      const int frow = qrow + lg * 4 + r;
      const int hd = hf * 16 + l15;
      const int d2 = ((frow & 7) << 5) + hd;
      x2b[bbase + (size_t)wid * 16384 + frow * 32 + hd] =
          __float2bfloat16(vv[hf][r] * rr * w[d2]);
    }
}

extern "C" void kernel_launch(void* const* d_in, const int* in_sizes, int n_in,
                              void* d_out, int out_size, void* d_ws, size_t ws_size,
                              hipStream_t stream)
{
  const float* emb     = (const float*)d_in[0];
  const float* pos_emb = (const float*)d_in[1];
  const float* attn_w  = (const float*)d_in[2];
  const float* wq      = (const float*)d_in[3];
  const float* bq      = (const float*)d_in[4];
  const float* wk      = (const float*)d_in[5];
  const float* bk      = (const float*)d_in[6];
  const float* wv      = (const float*)d_in[7];
  const float* bv      = (const float*)d_in[8];
  const float* cos_t   = (const float*)d_in[9];
  const float* sin_t   = (const float*)d_in[10];
  const float* ffn_w   = (const float*)d_in[11];
  const float* w_gate  = (const float*)d_in[12];
  const float* b_gate  = (const float*)d_in[13];
  const float* w_up    = (const float*)d_in[14];
  const float* b_up    = (const float*)d_in[15];
  const float* w_down  = (const float*)d_in[16];
  const float* b_down  = (const float*)d_in[17];
  const int*   tok     = (const int*)d_in[18];
  float* out = (float*)d_out;

  const size_t NT = (size_t)Bb * Ss;   // 8192
  char* base = (char*)d_ws;
  size_t off = 0;
  auto alloc = [&](size_t bytes) {
    void* r = base + off;
    off = (off + bytes + 255) & ~(size_t)255;
    return r;
  };
  bf16*  h_bf   = (bf16*)alloc(NT * Dd * 2);
  bf16*  x_bf   = (bf16*)alloc(NT * Dd * 2);
  bf16*  q_bf   = (bf16*)alloc(NT * Dd * 2);
  bf16*  k_bf   = (bf16*)alloc(NT * HDd * 2);
  bf16*  vt_bf  = (bf16*)alloc(NT * Dd * 2);
  bf16*  x2_bf  = (bf16*)alloc(NT * Dd * 2);
  bf16*  g_bf   = (bf16*)alloc(NT * (size_t)FKp * 2);
  bf16*  wqkv_b = (bf16*)alloc((size_t)640 * 256 * 2);
  bf16*  wgate_b= (bf16*)alloc((size_t)768 * 256 * 2);
  bf16*  wup_b  = (bf16*)alloc((size_t)768 * 256 * 2);
  bf16*  wdown_b= (bf16*)alloc((size_t)256 * FKp * 2);

  k_prep<<<dim3(720 + 2048), 256, 0, stream>>>(
      wq, wk, wv, w_gate, w_up, w_down, wqkv_b, wgate_b, wup_b, wdown_b,
      emb, pos_emb, tok, attn_w, h_bf, x_bf);

  k_qkv<<<dim3(NT / 64, 9), 256, 0, stream>>>(
      x_bf, wqkv_b, bq, bk, bv, cos_t, sin_t, q_bf, k_bf, vt_bf);

  k_attn_norm<<<dim3(32, Bb), 512, 0, stream>>>(
      q_bf, k_bf, vt_bf, h_bf, ffn_w, x2_bf);

  k_ffn<<<dim3(NT / 128, 22), 256, 0, stream>>>(
      x2_bf, wgate_b, wup_b, b_gate, b_up, g_bf);

  k_down<<<dim3(NT / 64, 8), 256, 0, stream>>>(
      g_bf, wdown_b, b_down, x2_bf, out);
}

// Round 21
// 76.372 us; speedup vs baseline: 1.0783x; 1.0066x over previous
//
#include <hip/hip_runtime.h>
#include <hip/hip_bf16.h>
#include <cstddef>
#include <cstdint>

constexpr int Bb = 16, Ss = 512, Dd = 256, Hh = 8, HDd = 32, Ff = 682;
constexpr int FKp = 704;            // padded K for down GEMM (682 -> 704 = 11*64)
constexpr float EPSf = 1.1920928955078125e-07f;

typedef short bf8v __attribute__((ext_vector_type(8)));
typedef float f4 __attribute__((ext_vector_type(4)));
using bf16 = __hip_bfloat16;

__device__ inline f4 MFMA(bf8v a, bf8v b, f4 c) {
  return __builtin_amdgcn_mfma_f32_16x16x32_bf16(a, b, c, 0, 0, 0);
}

__device__ __forceinline__ void pack4(bf16* dst, float a, float b, float c, float d) {
  bf16 t[4] = {__float2bfloat16(a), __float2bfloat16(b),
               __float2bfloat16(c), __float2bfloat16(d)};
  *(uint2*)dst = *(const uint2*)t;
}

// ---------------- vectorized weight converts + embed+rmsnorm in ONE launch ----
__global__ __launch_bounds__(256) void k_prep(
    const float* __restrict__ wq, const float* __restrict__ wk,
    const float* __restrict__ wv, const float* __restrict__ wg,
    const float* __restrict__ wu, const float* __restrict__ wd,
    bf16* __restrict__ dqkv, bf16* __restrict__ dgate,
    bf16* __restrict__ dup, bf16* __restrict__ ddown,
    const float* __restrict__ emb, const float* __restrict__ pos,
    const int* __restrict__ tok, const float* __restrict__ w,
    bf16* __restrict__ hb, bf16* __restrict__ xb)
{
  const int b = blockIdx.x, tid = threadIdx.x;
  if (b < 160) {                       // qkv pack
    const int idx4 = (b * 256 + tid) * 4;
    const int row = idx4 >> 8, col = idx4 & 255;
    f4 v = (f4){0.f, 0.f, 0.f, 0.f};
    if (row < 256)      v = *(const f4*)&wq[(size_t)row * 256 + col];
    else if (row < 288) v = *(const f4*)&wk[(size_t)(row - 256) * 256 + col];
    else if (row < 544) v = *(const f4*)&wv[(size_t)(row - 288) * 256 + col];
    pack4(&dqkv[idx4], v[0], v[1], v[2], v[3]);
  } else if (b < 544) {                // gate / up
    const bool isg = b < 352;
    const int idx4 = ((b - (isg ? 160 : 352)) * 256 + tid) * 4;
    const int row = idx4 >> 8, col = idx4 & 255;
    const float* src = isg ? wg : wu;
    f4 v = (f4){0.f, 0.f, 0.f, 0.f};
    if (row < Ff) v = *(const f4*)&src[(size_t)row * 256 + col];
    pack4(&(isg ? dgate : dup)[idx4], v[0], v[1], v[2], v[3]);
  } else if (b < 720) {                // down [256][704], src rows 682 wide
    const int idx4 = ((b - 544) * 256 + tid) * 4;
    const int row = idx4 / FKp, col = idx4 - row * FKp;   // col % 4 == 0
    float v0 = 0.f, v1 = 0.f, v2 = 0.f, v3 = 0.f;
    const float* srow = &wd[(size_t)row * Ff];
    if (col + 0 < Ff) v0 = srow[col + 0];
    if (col + 1 < Ff) v1 = srow[col + 1];
    if (col + 2 < Ff) v2 = srow[col + 2];
    if (col + 3 < Ff) v3 = srow[col + 3];
    pack4(&ddown[idx4], v0, v1, v2, v3);
  } else {                             // embed + rmsnorm, 4 rows/block
    const int row = (b - 720) * 4 + (tid >> 6);
    const int lane = tid & 63;
    const int c = lane * 4;
    const int s = row & (Ss - 1);
    const int t = tok[row];
    const f4 e4 = *(const f4*)&emb[(size_t)t * Dd + c];
    const f4 p4 = *(const f4*)&pos[(size_t)s * Dd + c];
    float v[4];
    float ss = 0.f;
    #pragma unroll
    for (int j = 0; j < 4; j++) { v[j] = e4[j] + p4[j]; ss += v[j] * v[j]; }
    #pragma unroll
    for (int x = 1; x < 64; x <<= 1) ss += __shfl_xor(ss, x);
    const float r = rsqrtf(ss * (1.0f / Dd) + EPSf);
    const f4 w4 = *(const f4*)&w[c];
    const size_t o = (size_t)row * Dd + c;
    pack4(&hb[o], v[0], v[1], v[2], v[3]);
    pack4(&xb[o], v[0] * r * w4[0], v[1] * r * w4[1],
                  v[2] * r * w4[2], v[3] * r * w4[3]);
  }
}

// ---------------- qkv GEMM: BM=64 BN=64 K=256, rope epilogue, V transposed ----
__global__ __launch_bounds__(256) void k_qkv(
    const bf16* __restrict__ A, const bf16* __restrict__ W,
    const float* __restrict__ bias0, const float* __restrict__ bias1,
    const float* __restrict__ bias2,
    const float* __restrict__ cost, const float* __restrict__ sint,
    bf16* __restrict__ ob0, bf16* __restrict__ ob1, bf16* __restrict__ vt)
{
  __shared__ bf16 As[64 * 72];
  __shared__ bf16 Bs[64 * 72];
  const int tid = threadIdx.x, lane = tid & 63, wid = tid >> 6;
  const int l15 = lane & 15, lg = lane >> 4;
  const int m0 = blockIdx.x * 64, n0 = blockIdx.y * 64;
  const int wr = (wid >> 1) * 32, wc = (wid & 1) * 32;
  const int srow = tid >> 3, scol = (tid & 7) * 8;   // srow 0..31

  f4 acc[2][2];
  #pragma unroll
  for (int i = 0; i < 2; i++)
    #pragma unroll
    for (int j = 0; j < 2; j++) acc[i][j] = (f4){0.f, 0.f, 0.f, 0.f};

  bf8v pa[2], pb[2];
  #pragma unroll
  for (int i = 0; i < 2; i++) {
    pa[i] = *(const bf8v*)&A[(size_t)(m0 + srow + i * 32) * 256 + scol];
    pb[i] = *(const bf8v*)&W[(size_t)(n0 + srow + i * 32) * 256 + scol];
  }
  #pragma unroll
  for (int i = 0; i < 2; i++) {
    *(bf8v*)&As[(srow + i * 32) * 72 + scol] = pa[i];
    *(bf8v*)&Bs[(srow + i * 32) * 72 + scol] = pb[i];
  }
  __syncthreads();

  for (int ks = 0; ks < 4; ks++) {
    if (ks < 3) {
      const int kn = (ks + 1) * 64;
      #pragma unroll
      for (int i = 0; i < 2; i++) {
        pa[i] = *(const bf8v*)&A[(size_t)(m0 + srow + i * 32) * 256 + kn + scol];
        pb[i] = *(const bf8v*)&W[(size_t)(n0 + srow + i * 32) * 256 + kn + scol];
      }
    }
    #pragma unroll
    for (int kk = 0; kk < 64; kk += 32) {
      bf8v af[2], bw[2];
      #pragma unroll
      for (int mi = 0; mi < 2; mi++)
        af[mi] = *(const bf8v*)&As[(wr + mi * 16 + l15) * 72 + kk + lg * 8];
      #pragma unroll
      for (int ni = 0; ni < 2; ni++)
        bw[ni] = *(const bf8v*)&Bs[(wc + ni * 16 + l15) * 72 + kk + lg * 8];
      #pragma unroll
      for (int mi = 0; mi < 2; mi++)
        #pragma unroll
        for (int ni = 0; ni < 2; ni++)
          acc[mi][ni] = MFMA(af[mi], bw[ni], acc[mi][ni]);
    }
    __syncthreads();
    if (ks < 3) {
      #pragma unroll
      for (int i = 0; i < 2; i++) {
        *(bf8v*)&As[(srow + i * 32) * 72 + scol] = pa[i];
        *(bf8v*)&Bs[(srow + i * 32) * 72 + scol] = pb[i];
      }
      __syncthreads();
    }
  }

  #pragma unroll
  for (int mi = 0; mi < 2; mi++) {
    #pragma unroll
    for (int ni = 0; ni < 2; ni++) {
      const int nbase = n0 + wc + ni * 16;
      const int n = nbase + l15;
      if (nbase < 288) {                      // q or k region: rope
        #pragma unroll
        for (int r = 0; r < 4; r++) {
          const int m = m0 + wr + mi * 16 + lg * 4 + r;
          float vb2 = acc[mi][ni][r] + (nbase < 256 ? bias0[n] : bias1[n - 256]);
          int s, hd;
          if (nbase < 256) { const int flat = ((m & 511) << 8) + n; s = (flat >> 5) & 511; hd = n & 31; }
          else             { s = m & 511; hd = n - 256; }
          const float c = cost[s * 32 + hd], sn = sint[s * 32 + hd];
          const float other = __shfl_xor(vb2, 1);
          const float res = (n & 1) ? (other * sn + vb2 * c) : (vb2 * c - other * sn);
          if (nbase < 256) ob0[(size_t)m * 256 + n] = __float2bfloat16(res);
          else             ob1[(size_t)m * 32 + hd] = __float2bfloat16(res);
        }
      } else if (nbase < 544) {               // v region: transpose via C-order reshape
        const int rel = n - 288;              // feature col in vlin, 0..255
        const int hd = rel & 31, rq = rel >> 5;
        const int mb = m0 + wr + mi * 16 + lg * 4;   // base row, mult of 4
        const int b = mb >> 9;
        const float bv = bias2[rel];
        #pragma unroll
        for (int r = 0; r < 4; r++) {
          const int s = (mb + r) & 511;
          // v4[b][h][s4][hd] = vlin[b][s][rel]:  h = s>>6, s4 = (s&63)*8 + rq
          const int hh2 = s >> 6;
          const int s4 = ((s & 63) << 3) + rq;
          vt[((size_t)(b * Hh + hh2) * HDd + hd) * Ss + s4] =
              __float2bfloat16(acc[mi][ni][r] + bv);
        }
      }
    }
  }
}

// ---------------- fused FFN gate+up: BM=64 BN=32 -> g_bf [8192][704] ----
__global__ __launch_bounds__(256) void k_ffn(
    const bf16* __restrict__ A, const bf16* __restrict__ Wg,
    const bf16* __restrict__ Wu,
    const float* __restrict__ bg, const float* __restrict__ bu,
    bf16* __restrict__ out)
{
  __shared__ bf16 As[64 * 72];
  __shared__ bf16 Gs[32 * 72];
  __shared__ bf16 Us[32 * 72];
  const int tid = threadIdx.x, lane = tid & 63, wid = tid >> 6;
  const int l15 = lane & 15, lg = lane >> 4;
  const int m0 = blockIdx.x * 64, n0 = blockIdx.y * 32;
  const int wr = (wid >> 1) * 32, wc = (wid & 1) * 16;
  const int srow = tid >> 3, scol = (tid & 7) * 8;   // srow 0..31
  const int wrow = tid >> 3;

  f4 accg[2], accu[2];
  #pragma unroll
  for (int i = 0; i < 2; i++) {
    accg[i] = (f4){0.f, 0.f, 0.f, 0.f};
    accu[i] = (f4){0.f, 0.f, 0.f, 0.f};
  }

  bf8v pa[2], pg, pu;
  #pragma unroll
  for (int i = 0; i < 2; i++)
    pa[i] = *(const bf8v*)&A[(size_t)(m0 + srow + i * 32) * 256 + scol];
  pg = *(const bf8v*)&Wg[(size_t)(n0 + wrow) * 256 + scol];
  pu = *(const bf8v*)&Wu[(size_t)(n0 + wrow) * 256 + scol];
  #pragma unroll
  for (int i = 0; i < 2; i++)
    *(bf8v*)&As[(srow + i * 32) * 72 + scol] = pa[i];
  *(bf8v*)&Gs[wrow * 72 + scol] = pg;
  *(bf8v*)&Us[wrow * 72 + scol] = pu;
  __syncthreads();

  for (int ks = 0; ks < 4; ks++) {
    if (ks < 3) {
      const int kn = (ks + 1) * 64;
      #pragma unroll
      for (int i = 0; i < 2; i++)
        pa[i] = *(const bf8v*)&A[(size_t)(m0 + srow + i * 32) * 256 + kn + scol];
      pg = *(const bf8v*)&Wg[(size_t)(n0 + wrow) * 256 + kn + scol];
      pu = *(const bf8v*)&Wu[(size_t)(n0 + wrow) * 256 + kn + scol];
    }
    #pragma unroll
    for (int kk = 0; kk < 64; kk += 32) {
      bf8v af[2], bgf, buf;
      #pragma unroll
      for (int mi = 0; mi < 2; mi++)
        af[mi] = *(const bf8v*)&As[(wr + mi * 16 + l15) * 72 + kk + lg * 8];
      bgf = *(const bf8v*)&Gs[(wc + l15) * 72 + kk + lg * 8];
      buf = *(const bf8v*)&Us[(wc + l15) * 72 + kk + lg * 8];
      #pragma unroll
      for (int mi = 0; mi < 2; mi++) {
        accg[mi] = MFMA(af[mi], bgf, accg[mi]);
        accu[mi] = MFMA(af[mi], buf, accu[mi]);
      }
    }
    __syncthreads();
    if (ks < 3) {
      #pragma unroll
      for (int i = 0; i < 2; i++)
        *(bf8v*)&As[(srow + i * 32) * 72 + scol] = pa[i];
      *(bf8v*)&Gs[wrow * 72 + scol] = pg;
      *(bf8v*)&Us[wrow * 72 + scol] = pu;
      __syncthreads();
    }
  }

  const int n = n0 + wc + l15;
  const float bgv = (n < Ff) ? bg[n] : 0.f;
  const float buv = (n < Ff) ? bu[n] : 0.f;
  #pragma unroll
  for (int mi = 0; mi < 2; mi++) {
    #pragma unroll
    for (int r = 0; r < 4; r++) {
      const int m = m0 + wr + mi * 16 + lg * 4 + r;
      float res = 0.f;
      if (n < Ff) {
        const float gv = accg[mi][r] + bgv;
        const float uv = accu[mi][r] + buv;
        res = gv / (1.f + __expf(-gv)) * uv;
      }
      out[(size_t)m * FKp + n] = __float2bfloat16(res);
    }
  }
}

// ---------------- down GEMM: BM=64 BN=32 K=704, +bias +resid(bf16) -> out f32 ----
__global__ __launch_bounds__(256) void k_down(
    const bf16* __restrict__ A, const bf16* __restrict__ W,
    const float* __restrict__ bias, const bf16* __restrict__ resid,
    float* __restrict__ out)
{
  __shared__ bf16 As[64 * 72];
  __shared__ bf16 Bs[32 * 72];
  const int tid = threadIdx.x, lane = tid & 63, wid = tid >> 6;
  const int l15 = lane & 15, lg = lane >> 4;
  const int m0 = blockIdx.x * 64, n0 = blockIdx.y * 32;
  const int wr = (wid >> 1) * 32, wc = (wid & 1) * 16;
  const int srow = tid >> 3, scol = (tid & 7) * 8;   // srow 0..31
  const int wrow = tid >> 3;

  f4 acc[2];
  acc[0] = (f4){0.f, 0.f, 0.f, 0.f};
  acc[1] = (f4){0.f, 0.f, 0.f, 0.f};

  bf8v pa[2], pb;
  #pragma unroll
  for (int i = 0; i < 2; i++)
    pa[i] = *(const bf8v*)&A[(size_t)(m0 + srow + i * 32) * FKp + scol];
  pb = *(const bf8v*)&W[(size_t)(n0 + wrow) * FKp + scol];
  #pragma unroll
  for (int i = 0; i < 2; i++)
    *(bf8v*)&As[(srow + i * 32) * 72 + scol] = pa[i];
  *(bf8v*)&Bs[wrow * 72 + scol] = pb;
  __syncthreads();

  for (int ks = 0; ks < 11; ks++) {
    if (ks < 10) {
      const int kn = (ks + 1) * 64;
      #pragma unroll
      for (int i = 0; i < 2; i++)
        pa[i] = *(const bf8v*)&A[(size_t)(m0 + srow + i * 32) * FKp + kn + scol];
      pb = *(const bf8v*)&W[(size_t)(n0 + wrow) * FKp + kn + scol];
    }
    #pragma unroll
    for (int kk = 0; kk < 64; kk += 32) {
      bf8v af[2], bw;
      #pragma unroll
      for (int mi = 0; mi < 2; mi++)
        af[mi] = *(const bf8v*)&As[(wr + mi * 16 + l15) * 72 + kk + lg * 8];
      bw = *(const bf8v*)&Bs[(wc + l15) * 72 + kk + lg * 8];
      #pragma unroll
      for (int mi = 0; mi < 2; mi++)
        acc[mi] = MFMA(af[mi], bw, acc[mi]);
    }
    __syncthreads();
    if (ks < 10) {
      #pragma unroll
      for (int i = 0; i < 2; i++)
        *(bf8v*)&As[(srow + i * 32) * 72 + scol] = pa[i];
      *(bf8v*)&Bs[wrow * 72 + scol] = pb;
      __syncthreads();
    }
  }

  const int n = n0 + wc + l15;
  const float bv = bias[n];
  #pragma unroll
  for (int mi = 0; mi < 2; mi++) {
    #pragma unroll
    for (int r = 0; r < 4; r++) {
      const int m = m0 + wr + mi * 16 + lg * 4 + r;
      out[(size_t)m * 256 + n] = acc[mi][r] + bv +
          __bfloat162float(resid[(size_t)m * 256 + n]);
    }
  }
}

// ---------------- fused attention + add + rmsnorm -> x2_bf only ----------------
// grid (32, B), 512 threads = 8 waves; wave = head wid, q-rows [(31-bx)*16,+16).
// o.reshape(B,S,D) is C-order: flat = h*16384 + s*32 + hd; a wave's 16 rows x
// 32 hd = exactly TWO full (B,S,D) rows (half-wave each) -> butterfly rmsnorm.
__global__ __launch_bounds__(512) void k_attn_norm(
    const bf16* __restrict__ q, const bf16* __restrict__ k,
    const bf16* __restrict__ vt, const bf16* __restrict__ hb,
    const float* __restrict__ w, bf16* __restrict__ x2b)
{
  __shared__ bf16 Ps[8][16 * 72];      // per wave P tile (18.4 KB)
  const int tid = threadIdx.x, lane = tid & 63, wid = tid >> 6;  // wid = head
  const int l15 = lane & 15, lg = lane >> 4;
  const int bb = blockIdx.y;
  const int bh = bb * Hh + wid;
  const int qrow = (31 - blockIdx.x) * 16;   // longest blocks dispatch first
  const int lt = (qrow + 15) >> 6;
  const float scale = 0.17677669529663687f;

  const bf16* kg = k + (size_t)bb * Ss * HDd;
  const bf16* vg = vt + (size_t)bh * (Ss * HDd);

  const bf8v qf = *(const bf8v*)&q[((size_t)bh * Ss + qrow + l15) * HDd + lg * 8];

  f4 oacc[2];
  oacc[0] = (f4){0.f, 0.f, 0.f, 0.f};
  oacc[1] = (f4){0.f, 0.f, 0.f, 0.f};
  float m = -3.0e38f, l = 0.f;

  for (int ti = 0; ti <= lt; ti++) {
    const int t0 = ti * 64;

    f4 sf[4];
    __builtin_amdgcn_s_setprio(1);
    #pragma unroll
    for (int tf = 0; tf < 4; tf++) {
      const bf8v kf = *(const bf8v*)&kg[(size_t)(t0 + tf * 16 + l15) * HDd + lg * 8];
      sf[tf] = MFMA(kf, qf, (f4){0.f, 0.f, 0.f, 0.f});
    }
    __builtin_amdgcn_s_setprio(0);

    bf8v vb[2][2];
    #pragma unroll
    for (int kt = 0; kt < 2; kt++)
      #pragma unroll
      for (int hf = 0; hf < 2; hf++)
        vb[kt][hf] = *(const bf8v*)&vg[(size_t)(hf * 16 + l15) * Ss + t0 + kt * 32 + lg * 8];

    float pm = -3.0e38f;
    if (ti == lt) {
      #pragma unroll
      for (int tf = 0; tf < 4; tf++)
        #pragma unroll
        for (int r = 0; r < 4; r++) {
          float sv = sf[tf][r] * scale;
          if (t0 + tf * 16 + lg * 4 + r > qrow + l15) sv = -3.0e38f;
          sf[tf][r] = sv;
          pm = fmaxf(pm, sv);
        }
    } else {
      #pragma unroll
      for (int tf = 0; tf < 4; tf++)
        #pragma unroll
        for (int r = 0; r < 4; r++) {
          const float sv = sf[tf][r] * scale;
          sf[tf][r] = sv;
          pm = fmaxf(pm, sv);
        }
    }
    pm = fmaxf(pm, __shfl_xor(pm, 16));
    pm = fmaxf(pm, __shfl_xor(pm, 32));

    const float nm = fmaxf(m, pm);
    const float corr = __expf(m - nm);
    m = nm;

    float ls = 0.f;
    #pragma unroll
    for (int tf = 0; tf < 4; tf++)
      #pragma unroll
      for (int r = 0; r < 4; r++) {
        const float p = __expf(sf[tf][r] - m);
        sf[tf][r] = p;
        ls += p;
      }
    ls += __shfl_xor(ls, 16);
    ls += __shfl_xor(ls, 32);
    l = l * corr + ls;

    #pragma unroll
    for (int tf = 0; tf < 4; tf++) {
      bf16 t4[4];
      #pragma unroll
      for (int r = 0; r < 4; r++) t4[r] = __float2bfloat16(sf[tf][r]);
      *(uint2*)&Ps[wid][l15 * 72 + tf * 16 + lg * 4] = *(const uint2*)t4;
    }

    float corrT[4];
    #pragma unroll
    for (int r = 0; r < 4; r++) corrT[r] = __shfl(corr, lg * 4 + r);
    #pragma unroll
    for (int hf = 0; hf < 2; hf++)
      #pragma unroll
      for (int r = 0; r < 4; r++) oacc[hf][r] *= corrT[r];

    __builtin_amdgcn_s_setprio(1);
    #pragma unroll
    for (int kt = 0; kt < 2; kt++) {
      const bf8v pv = *(const bf8v*)&Ps[wid][l15 * 72 + kt * 32 + lg * 8];
      #pragma unroll
      for (int hf = 0; hf < 2; hf++)
        oacc[hf] = MFMA(pv, vb[kt][hf], oacc[hf]);
    }
    __builtin_amdgcn_s_setprio(0);
  }

  // ---- fused add + rmsnorm in the reshaped (B,S,D) space ----
  float lT[4];
  #pragma unroll
  for (int r = 0; r < 4; r++) lT[r] = __shfl(l, lg * 4 + r);

  const size_t bbase = (size_t)bb * (Ss * Dd);
  float vv[2][4];
  #pragma unroll
  for (int hf = 0; hf < 2; hf++)
    #pragma unroll
    for (int r = 0; r < 4; r++) {
      const int frow = qrow + lg * 4 + r;
      const int hd = hf * 16 + l15;
      vv[hf][r] = oacc[hf][r] / lT[r] +
          __bfloat162float(hb[bbase + (size_t)wid * 16384 + frow * 32 + hd]);
    }

  float ss = 0.f;
  #pragma unroll
  for (int hf = 0; hf < 2; hf++)
    #pragma unroll
    for (int r = 0; r < 4; r++) ss += vv[hf][r] * vv[hf][r];
  #pragma unroll
  for (int x = 1; x < 32; x <<= 1) ss += __shfl_xor(ss, x);   // half-wave sum
  const float rr = rsqrtf(ss * (1.0f / Dd) + EPSf);

  #pragma unroll
  for (int hf = 0; hf < 2; hf++)
    #pragma unroll
    for (int r = 0; r < 4; r++) {
      const int frow = qrow + lg * 4 + r;
      const int hd = hf * 16 + l15;
      const int d2 = ((frow & 7) << 5) + hd;
      x2b[bbase + (size_t)wid * 16384 + frow * 32 + hd] =
          __float2bfloat16(vv[hf][r] * rr * w[d2]);
    }
}

extern "C" void kernel_launch(void* const* d_in, const int* in_sizes, int n_in,
                              void* d_out, int out_size, void* d_ws, size_t ws_size,
                              hipStream_t stream)
{
  const float* emb     = (const float*)d_in[0];
  const float* pos_emb = (const float*)d_in[1];
  const float* attn_w  = (const float*)d_in[2];
  const float* wq      = (const float*)d_in[3];
  const float* bq      = (const float*)d_in[4];
  const float* wk      = (const float*)d_in[5];
  const float* bk      = (const float*)d_in[6];
  const float* wv      = (const float*)d_in[7];
  const float* bv      = (const float*)d_in[8];
  const float* cos_t   = (const float*)d_in[9];
  const float* sin_t   = (const float*)d_in[10];
  const float* ffn_w   = (const float*)d_in[11];
  const float* w_gate  = (const float*)d_in[12];
  const float* b_gate  = (const float*)d_in[13];
  const float* w_up    = (const float*)d_in[14];
  const float* b_up    = (const float*)d_in[15];
  const float* w_down  = (const float*)d_in[16];
  const float* b_down  = (const float*)d_in[17];
  const int*   tok     = (const int*)d_in[18];
  float* out = (float*)d_out;

  const size_t NT = (size_t)Bb * Ss;   // 8192
  char* base = (char*)d_ws;
  size_t off = 0;
  auto alloc = [&](size_t bytes) {
    void* r = base + off;
    off = (off + bytes + 255) & ~(size_t)255;
    return r;
  };
  bf16*  h_bf   = (bf16*)alloc(NT * Dd * 2);
  bf16*  x_bf   = (bf16*)alloc(NT * Dd * 2);
  bf16*  q_bf   = (bf16*)alloc(NT * Dd * 2);
  bf16*  k_bf   = (bf16*)alloc(NT * HDd * 2);
  bf16*  vt_bf  = (bf16*)alloc(NT * Dd * 2);
  bf16*  x2_bf  = (bf16*)alloc(NT * Dd * 2);
  bf16*  g_bf   = (bf16*)alloc(NT * (size_t)FKp * 2);
  bf16*  wqkv_b = (bf16*)alloc((size_t)640 * 256 * 2);
  bf16*  wgate_b= (bf16*)alloc((size_t)768 * 256 * 2);
  bf16*  wup_b  = (bf16*)alloc((size_t)768 * 256 * 2);
  bf16*  wdown_b= (bf16*)alloc((size_t)256 * FKp * 2);

  k_prep<<<dim3(720 + 2048), 256, 0, stream>>>(
      wq, wk, wv, w_gate, w_up, w_down, wqkv_b, wgate_b, wup_b, wdown_b,
      emb, pos_emb, tok, attn_w, h_bf, x_bf);

  k_qkv<<<dim3(NT / 64, 9), 256, 0, stream>>>(
      x_bf, wqkv_b, bq, bk, bv, cos_t, sin_t, q_bf, k_bf, vt_bf);

  k_attn_norm<<<dim3(32, Bb), 512, 0, stream>>>(
      q_bf, k_bf, vt_bf, h_bf, ffn_w, x2_bf);

  k_ffn<<<dim3(NT / 64, 22), 256, 0, stream>>>(
      x2_bf, wgate_b, wup_b, b_gate, b_up, g_bf);

  k_down<<<dim3(NT / 64, 8), 256, 0, stream>>>(
      g_bf, wdown_b, b_down, x2_bf, out);
}